// Round 4
// baseline (60759.918 us; speedup 1.0000x reference)
//
#include <hip/hip_runtime.h>

typedef unsigned short u16;
typedef __attribute__((ext_vector_type(8))) short bf16x8;
typedef __attribute__((ext_vector_type(4))) float f32x4;

// ---------------- constants ----------------
#define Bsz   128
#define TIN   512
#define TOUT  64
#define INF   64
#define OUTF  32
#define Hdim  1024
#define H3    3072

// K layouts: H-PART FIRST everywhere (uniform n-gate split at kb=32)
#define K0    1088   // enc L0: [h(1024) | x(64)]
#define K1    2048   // enc L1: [h1(1024) | y0(1024)]
#define KD0   1120   // dec L0: [h(1024) | yp(32) x(64)]
#define KD1   2048   // dec L1: [h1(1024) | h0(1024)]
#define KH    1024

#define SX0  (Bsz * K0)
#define SX1  (Bsz * K1)
#define SXD0 (Bsz * KD0)
#define SXD1 (Bsz * KD1)
#define SH   (Bsz * Hdim)

// barrier layout in u32 words: leaves at i*16 (i<32), root at 512, gen at 528
#define BAR_ROOT 512
#define BAR_GEN  528
#define BAR_WORDS 544

__device__ __forceinline__ u16 f2bf(float f) {
    union { float f; unsigned u; } c; c.f = f;
    unsigned u = c.u;
    unsigned r = (u + 0x7fffu + ((u >> 16) & 1u)) >> 16;
    return (u16)r;
}

__device__ __forceinline__ f32x4 mfma16(bf16x8 a, bf16x8 b, f32x4 c) {
    return __builtin_amdgcn_mfma_f32_16x16x32_bf16(a, b, c, 0, 0, 0);
}

// ---------------- software grid barrier (multi-XCD safe) ----------------
// Generation-based, hierarchical (32 leaves x 8 blocks -> root -> gen).
// Arrivals/polls are AGENT-scope atomics (L2-bypassing); __threadfence gives
// release (vmcnt drain + L2 wb) / acquire (L1+L2 inv) for the data arrays.
__device__ __forceinline__ void gridbar(unsigned* bar, unsigned target) {
    __syncthreads();
    if (threadIdx.x == 0) {
        __threadfence();   // release: drain stores, write back dirty L2
        unsigned leaf = (blockIdx.x >> 3) << 4;
        unsigned a = __hip_atomic_fetch_add(&bar[leaf], 1u,
                        __ATOMIC_RELEASE, __HIP_MEMORY_SCOPE_AGENT);
        if (((a + 1u) & 7u) == 0u) {
            unsigned r = __hip_atomic_fetch_add(&bar[BAR_ROOT], 1u,
                            __ATOMIC_ACQ_REL, __HIP_MEMORY_SCOPE_AGENT);
            if (((r + 1u) & 31u) == 0u)
                __hip_atomic_fetch_add(&bar[BAR_GEN], 1u,
                        __ATOMIC_RELEASE, __HIP_MEMORY_SCOPE_AGENT);
        }
        while (__hip_atomic_load(&bar[BAR_GEN],
                    __ATOMIC_ACQUIRE, __HIP_MEMORY_SCOPE_AGENT) < target)
            __builtin_amdgcn_s_sleep(2);
        __threadfence();   // acquire: invalidate L1/L2 so fresh state is read
    }
    __syncthreads();
}

// ---------------- prologue kernels ----------------

__global__ void __launch_bounds__(256) pack2(
        const float* __restrict__ A, int KA,
        const float* __restrict__ Bs, int KB,
        u16* __restrict__ dst) {
    int row = blockIdx.y;
    int k = blockIdx.x * 256 + threadIdx.x;
    int K = KA + KB;
    if (k >= K) return;
    float v = (k < KA) ? A[(size_t)row * KA + k] : Bs[(size_t)row * KB + (k - KA)];
    dst[(size_t)row * K + k] = f2bf(v);
}

// Bias packs: [br+bhr | bz+bhz | bin | bhn] each 1024
__global__ void __launch_bounds__(256) pack_bias(
        const float* bi0e, const float* bh0e,
        const float* bi1e, const float* bh1e,
        const float* bi0d, const float* bh0d,
        const float* bi1d, const float* bh1d,
        const float* out1b,
        float* B0, float* B1, float* BD0, float* BD1, float* HB) {
    int j = blockIdx.x * blockDim.x + threadIdx.x;
    if (j >= 1024) return;
    const float* bis[4] = { bi0e, bi1e, bi0d, bi1d };
    const float* bhs[4] = { bh0e, bh1e, bh0d, bh1d };
    float* ds[4] = { B0, B1, BD0, BD1 };
#pragma unroll
    for (int s = 0; s < 4; ++s) {
        ds[s][j]        = bis[s][j]        + bhs[s][j];
        ds[s][1024 + j] = bis[s][1024 + j] + bhs[s][1024 + j];
        ds[s][2048 + j] = bis[s][2048 + j];
        ds[s][3072 + j] = bhs[s][2048 + j];
    }
    HB[j] = out1b[j];
}

__global__ void __launch_bounds__(256) init_state(
        const float* __restrict__ enc_input,
        u16* __restrict__ X0, u16* __restrict__ X1,
        float* __restrict__ H0f, float* __restrict__ H1f,
        unsigned* __restrict__ bar) {
    int gtid = blockIdx.x * blockDim.x + threadIdx.x;
    int G = gridDim.x * blockDim.x;
    for (int i = gtid; i < BAR_WORDS; i += G) bar[i] = 0u;
    for (int i = gtid; i < Bsz * Hdim; i += G) { int b = i >> 10, j = i & 1023; X0[(size_t)b * K0 + j] = 0; }
    for (int i = gtid; i < Bsz * INF; i += G) { int b = i >> 6, f = i & 63;
        X0[(size_t)b * K0 + 1024 + f] = f2bf(enc_input[(size_t)b * (TIN * INF) + f]); }
    // X1 parity1: h1-part (offset 0) = 0
    for (int i = gtid; i < Bsz * Hdim; i += G) { int b = i >> 10, j = i & 1023;
        X1[(size_t)SX1 + (size_t)b * K1 + j] = 0; }
    for (int i = gtid; i < Bsz * Hdim; i += G) { H0f[i] = 0.f; H1f[SH + i] = 0.f; }
}

// ---------------- K-split GRU wave ----------------
template <int KB0, int KB1, int SPLIT>
__device__ __forceinline__ void gru_wave(
        const u16* __restrict__ W, const u16* __restrict__ X, int K,
        int j0, int nb0w,
        f32x4& accR, f32x4& accZ, f32x4& accN0, f32x4& accN1) {
    const int lane = threadIdx.x & 63;
    const int l15 = lane & 15, kq = lane >> 4;
    const u16* Wr = W + (size_t)(j0 + l15) * K + kq * 8;
    const u16* Wz = Wr + (size_t)1024 * K;
    const u16* Wn = Wz + (size_t)1024 * K;
    const u16* Xb = X + (size_t)(nb0w + l15) * K + kq * 8;
    accR = (f32x4){0.f, 0.f, 0.f, 0.f};
    accZ = (f32x4){0.f, 0.f, 0.f, 0.f};
    accN0 = (f32x4){0.f, 0.f, 0.f, 0.f};
    accN1 = (f32x4){0.f, 0.f, 0.f, 0.f};
    constexpr int E0 = (SPLIT < KB1) ? SPLIT : KB1;
    constexpr int S1 = (SPLIT > KB0) ? SPLIT : KB0;
#pragma unroll 8
    for (int kb = KB0; kb < E0; ++kb) {
        const int o = kb * 32;
        bf16x8 xb = *(const bf16x8*)(Xb + o);
        accR  = mfma16(*(const bf16x8*)(Wr + o), xb, accR);
        accZ  = mfma16(*(const bf16x8*)(Wz + o), xb, accZ);
        accN0 = mfma16(*(const bf16x8*)(Wn + o), xb, accN0);
    }
#pragma unroll 8
    for (int kb = S1; kb < KB1; ++kb) {
        const int o = kb * 32;
        bf16x8 xb = *(const bf16x8*)(Xb + o);
        accR  = mfma16(*(const bf16x8*)(Wr + o), xb, accR);
        accZ  = mfma16(*(const bf16x8*)(Wz + o), xb, accZ);
        accN1 = mfma16(*(const bf16x8*)(Wn + o), xb, accN1);
    }
}

// ---------------- WG-level GRU tile: 16 h-rows x 64 batch, K split over 2
// wave groups (waves 0-3 = kb [0,MID), waves 4-7 = kb [MID,KBT)), LDS combine.
template <int KBT, int SPLIT>
__device__ __forceinline__ void gru_block(
        const u16* __restrict__ W, const u16* __restrict__ X,
        const float* __restrict__ Hold, const float* __restrict__ Bias,
        int K, int ct, int nb0,
        float* __restrict__ Hnew,
        u16* __restrict__ O1, int ld1, int off1,
        u16* __restrict__ O2, int ld2, int off2,
        float* __restrict__ sred /* [4][64][17] */) {
    const int tid = threadIdx.x, lane = tid & 63, w = tid >> 6;
    const int bg = w & 3, grp = w >> 2;
    const int l15 = lane & 15, kq = lane >> 4;
    const int j0 = ct * 16;
    const int nb0w = nb0 + bg * 16;
    constexpr int MID = KBT / 2;

    f32x4 aR, aZ, aN0, aN1;
    if (grp == 0) gru_wave<0, MID, SPLIT>(W, X, K, j0, nb0w, aR, aZ, aN0, aN1);
    else          gru_wave<MID, KBT, SPLIT>(W, X, K, j0, nb0w, aR, aZ, aN0, aN1);

    float* slot = sred + ((size_t)bg * 64 + lane) * 17;
    if (grp == 1) {
#pragma unroll
        for (int q = 0; q < 4; ++q) {
            slot[q]      = aR[q];
            slot[4 + q]  = aZ[q];
            slot[8 + q]  = aN0[q];
            slot[12 + q] = aN1[q];
        }
    }
    __syncthreads();
    if (grp == 0) {
#pragma unroll
        for (int q = 0; q < 4; ++q) {
            const int j = j0 + kq * 4 + q;
            const int nb = nb0w + l15;
            float R  = aR[q]  + slot[q];
            float Z  = aZ[q]  + slot[4 + q];
            float Nh = aN0[q] + slot[8 + q];
            float Ni = aN1[q] + slot[12 + q];
            float r = 1.f / (1.f + expf(-(R + Bias[j])));
            float z = 1.f / (1.f + expf(-(Z + Bias[1024 + j])));
            float n = tanhf(Ni + Bias[2048 + j] + r * (Nh + Bias[3072 + j]));
            float ho = Hold[(size_t)j * Bsz + nb];
            float hv = (1.f - z) * n + z * ho;
            Hnew[(size_t)j * Bsz + nb] = hv;
            u16 hb = f2bf(hv);
            O1[(size_t)nb * ld1 + off1 + j] = hb;
            if (O2) O2[(size_t)nb * ld2 + off2 + j] = hb;
        }
    }
}

// ---------------- params ----------------
struct KParams {
    const float* enc_input;
    const float* dec_input;
    const u16 *W0, *W1, *WD0, *WD1, *WH1, *WH2;
    const float *B0, *B1, *BD0, *BD1, *HB;
    u16 *X0, *X1, *XD0, *XD1, *Hhead, *Abuf;
    float *H0f, *H1f;
    float* out;
    unsigned* bar;
};

// ---------------- round bodies (device functions) ----------------

__device__ __forceinline__ void enc_round_body(const KParams& p, int r, float* sred) {
    const int wg = blockIdx.x;
    const int pr = r & 1, pw = pr ^ 1;
    if (wg < 128) {
        if (r < 512) {
            gru_block<34, 32>(p.W0, p.X0 + pr * SX0, p.H0f + pr * SH, p.B0,
                              K0, wg >> 1, (wg & 1) * 64,
                              p.H0f + pw * SH,
                              p.X0 + pw * SX0, K0, 0,
                              p.X1 + pw * SX1, K1, 1024, sred);
            if (r + 1 < 512 && threadIdx.x < 64) {
                int b = wg, f = threadIdx.x;
                p.X0[(size_t)pw * SX0 + (size_t)b * K0 + 1024 + f] =
                    f2bf(p.enc_input[((size_t)b * TIN + (r + 1)) * INF + f]);
            }
        }
    } else {
        if (r >= 1) {
            int w2 = wg - 128;
            gru_block<64, 32>(p.W1, p.X1 + pr * SX1, p.H1f + pr * SH, p.B1,
                              K1, w2 >> 1, (w2 & 1) * 64,
                              p.H1f + pw * SH,
                              p.X1 + pw * SX1, K1, 0,
                              (u16*)nullptr, 0, 0, sred);
        }
    }
}

__device__ __forceinline__ void transition_body(const KParams& p) {
    int gtid = blockIdx.x * blockDim.x + threadIdx.x;
    const int G = 256 * 512;
    for (int i = gtid; i < SH; i += G) p.H1f[i] = p.H1f[SH + i];
    for (int i = gtid; i < Bsz * Hdim; i += G) {
        int b = i >> 10, j = i & 1023;
        p.XD0[(size_t)b * KD0 + j] = p.X0[(size_t)b * K0 + j];  // eh0 bf16 (parity0)
    }
    for (int i = gtid; i < Bsz * OUTF; i += G) {
        int b = i >> 5, f = i & 31;
        p.XD0[(size_t)b * KD0 + 1024 + f] = f2bf(p.enc_input[((size_t)b * TIN + (TIN - 1)) * INF + f]);
    }
    for (int i = gtid; i < Bsz * INF; i += G) {
        int b = i >> 6, f = i & 63;
        p.XD0[(size_t)b * KD0 + 1056 + f] = f2bf(p.dec_input[(size_t)b * (TOUT * INF) + f]);
    }
    for (int i = gtid; i < Bsz * Hdim; i += G) {
        int b = i >> 10, j = i & 1023;
        p.XD1[(size_t)b * KD1 + j] = p.X1[(size_t)SX1 + (size_t)b * K1 + j];  // eh1 bf16
    }
}

__device__ __forceinline__ void dec_A_body(const KParams& p, int t, float* sred) {
    const int wg = blockIdx.x;
    const int pt = t & 1, pn = pt ^ 1;
    gru_block<35, 32>(p.WD0, p.XD0 + pt * SXD0, p.H0f + pt * SH, p.BD0,
                      KD0, wg >> 1, (wg & 1) * 64,
                      p.H0f + pn * SH,
                      p.XD0 + pn * SXD0, KD0, 0,
                      p.XD1 + pt * SXD1, KD1, 1024, sred);
}

__device__ __forceinline__ void dec_B_body(const KParams& p, int t, float* sred) {
    const int wg = blockIdx.x;
    const int pt = t & 1, pn = pt ^ 1;
    gru_block<64, 32>(p.WD1, p.XD1 + pt * SXD1, p.H1f + pt * SH, p.BD1,
                      KD1, wg >> 1, (wg & 1) * 64,
                      p.H1f + pn * SH,
                      p.XD1 + pn * SXD1, KD1, 0,
                      p.Hhead, KH, 0, sred);
}

// a = relu(h1 @ W1^T + b); also stage x_{t+1}. waves 0-3 active.
__device__ __forceinline__ void dec_C_body(const KParams& p, int t) {
    const int wg = blockIdx.x;
    const int pn = (t & 1) ^ 1;
    const int tid = threadIdx.x, lane = tid & 63, w = tid >> 6;
    if (w < 4) {
        const int l15 = lane & 15, kq = lane >> 4;
        const int ct = wg >> 1, nb0 = (wg & 1) * 64;
        const int j0 = ct * 16;
        const int nb = nb0 + w * 16 + l15;
        const u16* Wr = p.WH1 + (size_t)(j0 + l15) * KH + kq * 8;
        const u16* Xb = p.Hhead + (size_t)nb * KH + kq * 8;
        f32x4 acc = {0.f, 0.f, 0.f, 0.f};
#pragma unroll 8
        for (int kb = 0; kb < KH / 32; ++kb) {
            const int o = kb * 32;
            acc = mfma16(*(const bf16x8*)(Wr + o), *(const bf16x8*)(Xb + o), acc);
        }
#pragma unroll
        for (int q = 0; q < 4; ++q) {
            const int j = j0 + kq * 4 + q;
            float v = acc[q] + p.HB[j];
            v = v > 0.f ? v : 0.f;
            p.Abuf[(size_t)nb * KH + j] = f2bf(v);
        }
        if (t + 1 < TOUT && tid < 64) {
            int b = wg, f = tid;
            p.XD0[(size_t)pn * SXD0 + (size_t)b * KD0 + 1056 + f] =
                f2bf(p.dec_input[((size_t)b * TOUT + (t + 1)) * INF + f]);
        }
    }
}

// out = a @ W2^T (32 x 128), blocks 0-15, waves 0-3 split K, LDS-reduce.
// NOTE: contains __syncthreads — all 512 threads of participating blocks enter.
__device__ __forceinline__ void dec_D_body(const KParams& p, int t, float* sred) {
    const int wg = blockIdx.x;
    const int pn = (t & 1) ^ 1;
    const int tid = threadIdx.x, lane = tid & 63, w = tid >> 6;
    const int l15 = lane & 15, kq = lane >> 4;
    const int mt = wg & 1, nt = wg >> 1;
    if (w < 4) {
        const u16* Wr = p.WH2 + (size_t)(mt * 16 + l15) * KH + kq * 8;
        const u16* Xb = p.Abuf + (size_t)(nt * 16 + l15) * KH + kq * 8;
        f32x4 acc = {0.f, 0.f, 0.f, 0.f};
#pragma unroll 8
        for (int kb = w * 8; kb < w * 8 + 8; ++kb) {
            const int o = kb * 32;
            acc = mfma16(*(const bf16x8*)(Wr + o), *(const bf16x8*)(Xb + o), acc);
        }
#pragma unroll
        for (int q = 0; q < 4; ++q) sred[(w * 64 + lane) * 4 + q] = acc[q];
    }
    __syncthreads();
    if (w == 0) {
#pragma unroll
        for (int q = 0; q < 4; ++q) {
            float s = sred[(0 * 64 + lane) * 4 + q] + sred[(1 * 64 + lane) * 4 + q] +
                      sred[(2 * 64 + lane) * 4 + q] + sred[(3 * 64 + lane) * 4 + q];
            int feat = mt * 16 + kq * 4 + q;
            int b = nt * 16 + l15;
            p.out[(size_t)b * (TOUT * OUTF) + t * OUTF + feat] = s;
            p.XD0[(size_t)pn * SXD0 + (size_t)b * KD0 + 1024 + feat] = f2bf(s);
        }
    }
}

// ---------------- the persistent kernel ----------------
__global__ void __launch_bounds__(512, 1) seq2seq_persist(KParams p) {
    __shared__ float sred[4 * 64 * 17];
    unsigned target = 0;

    // encoder: 513 pipelined rounds
    for (int r = 0; r < 513; ++r) {
        enc_round_body(p, r, sred);
        gridbar(p.bar, ++target);
    }

    // transition
    transition_body(p);
    gridbar(p.bar, ++target);

    // decoder: 64 steps x 4 rounds
    for (int t = 0; t < TOUT; ++t) {
        if (blockIdx.x < 128) dec_A_body(p, t, sred);
        gridbar(p.bar, ++target);
        if (blockIdx.x < 128) dec_B_body(p, t, sred);
        gridbar(p.bar, ++target);
        if (blockIdx.x < 128) dec_C_body(p, t);
        gridbar(p.bar, ++target);
        if (blockIdx.x < 16) dec_D_body(p, t, sred);
        if (t + 1 < TOUT) gridbar(p.bar, ++target);
    }
}

// ---------------- host launch ----------------
extern "C" void kernel_launch(void* const* d_in, const int* in_sizes, int n_in,
                              void* d_out, int out_size, void* d_ws, size_t ws_size,
                              hipStream_t stream) {
    const float* enc_input = (const float*)d_in[0];
    const float* dec_input = (const float*)d_in[1];
    const float* enc_Wih0 = (const float*)d_in[2];
    const float* enc_Whh0 = (const float*)d_in[3];
    const float* enc_bih0 = (const float*)d_in[4];
    const float* enc_bhh0 = (const float*)d_in[5];
    const float* enc_Wih1 = (const float*)d_in[6];
    const float* enc_Whh1 = (const float*)d_in[7];
    const float* enc_bih1 = (const float*)d_in[8];
    const float* enc_bhh1 = (const float*)d_in[9];
    const float* dec_Wih0 = (const float*)d_in[10];
    const float* dec_Whh0 = (const float*)d_in[11];
    const float* dec_bih0 = (const float*)d_in[12];
    const float* dec_bhh0 = (const float*)d_in[13];
    const float* dec_Wih1 = (const float*)d_in[14];
    const float* dec_Whh1 = (const float*)d_in[15];
    const float* dec_bih1 = (const float*)d_in[16];
    const float* dec_bhh1 = (const float*)d_in[17];
    const float* out1_W = (const float*)d_in[18];
    const float* out1_b = (const float*)d_in[19];
    const float* out2_W = (const float*)d_in[20];

    char* ws = (char*)d_ws;
    size_t off = 0;
    auto alloc = [&](size_t bytes) { size_t o = off; off = (off + bytes + 255) & ~(size_t)255; return o; };

    u16* W0 = (u16*)(ws + alloc((size_t)H3 * K0 * 2));
    u16* W1 = (u16*)(ws + alloc((size_t)H3 * K1 * 2));
    u16* WD0 = (u16*)(ws + alloc((size_t)H3 * KD0 * 2));
    u16* WD1 = (u16*)(ws + alloc((size_t)H3 * KD1 * 2));
    u16* WH1 = (u16*)(ws + alloc((size_t)Hdim * KH * 2));
    u16* WH2 = (u16*)(ws + alloc((size_t)OUTF * KH * 2));
    float* B0 = (float*)(ws + alloc(4096 * 4));
    float* B1 = (float*)(ws + alloc(4096 * 4));
    float* BD0 = (float*)(ws + alloc(4096 * 4));
    float* BD1 = (float*)(ws + alloc(4096 * 4));
    float* HB = (float*)(ws + alloc(1024 * 4));
    u16* X0 = (u16*)(ws + alloc((size_t)2 * Bsz * K0 * 2));
    u16* X1 = (u16*)(ws + alloc((size_t)2 * Bsz * K1 * 2));
    u16* XD0 = (u16*)(ws + alloc((size_t)2 * Bsz * KD0 * 2));
    u16* XD1 = (u16*)(ws + alloc((size_t)2 * Bsz * KD1 * 2));
    float* H0f = (float*)(ws + alloc((size_t)2 * Bsz * Hdim * 4));
    float* H1f = (float*)(ws + alloc((size_t)2 * Bsz * Hdim * 4));
    u16* Hhead = (u16*)(ws + alloc((size_t)Bsz * KH * 2));
    u16* Abuf = (u16*)(ws + alloc((size_t)Bsz * KH * 2));
    unsigned* bar = (unsigned*)(ws + alloc(BAR_WORDS * 4));

    // --- prologue: weight/bias repack (h-part FIRST) + state/barrier init ---
    pack2<<<dim3((K0 + 255) / 256, H3), 256, 0, stream>>>(enc_Whh0, 1024, enc_Wih0, 64, W0);
    pack2<<<dim3((K1 + 255) / 256, H3), 256, 0, stream>>>(enc_Whh1, 1024, enc_Wih1, 1024, W1);
    pack2<<<dim3((KD0 + 255) / 256, H3), 256, 0, stream>>>(dec_Whh0, 1024, dec_Wih0, 96, WD0);
    pack2<<<dim3((KD1 + 255) / 256, H3), 256, 0, stream>>>(dec_Whh1, 1024, dec_Wih1, 1024, WD1);
    pack2<<<dim3((KH + 255) / 256, Hdim), 256, 0, stream>>>(out1_W, 1024, nullptr, 0, WH1);
    pack2<<<dim3((KH + 255) / 256, OUTF), 256, 0, stream>>>(out2_W, 1024, nullptr, 0, WH2);
    pack_bias<<<4, 256, 0, stream>>>(enc_bih0, enc_bhh0, enc_bih1, enc_bhh1,
                                     dec_bih0, dec_bhh0, dec_bih1, dec_bhh1,
                                     out1_b, B0, B1, BD0, BD1, HB);
    init_state<<<256, 256, 0, stream>>>(enc_input, X0, X1, H0f, H1f, bar);

    KParams kp;
    kp.enc_input = enc_input; kp.dec_input = dec_input;
    kp.W0 = W0; kp.W1 = W1; kp.WD0 = WD0; kp.WD1 = WD1; kp.WH1 = WH1; kp.WH2 = WH2;
    kp.B0 = B0; kp.B1 = B1; kp.BD0 = BD0; kp.BD1 = BD1; kp.HB = HB;
    kp.X0 = X0; kp.X1 = X1; kp.XD0 = XD0; kp.XD1 = XD1; kp.Hhead = Hhead; kp.Abuf = Abuf;
    kp.H0f = H0f; kp.H1f = H1f;
    kp.out = (float*)d_out;
    kp.bar = bar;

    // --- one persistent kernel: software grid barrier between rounds ---
    seq2seq_persist<<<256, 512, 0, stream>>>(kp);
}

// Round 5
// 29827.628 us; speedup vs baseline: 2.0370x; 2.0370x over previous
//
#include <hip/hip_runtime.h>

typedef unsigned short u16;
typedef unsigned long long u64;
typedef __attribute__((ext_vector_type(8))) short bf16x8;
typedef __attribute__((ext_vector_type(4))) float f32x4;

// ---------------- constants ----------------
#define Bsz   128
#define TIN   512
#define TOUT  64
#define INF   64
#define OUTF  32
#define Hdim  1024
#define H3    3072

// K layouts: H-PART FIRST everywhere (uniform n-gate split at kb=32)
#define K0    1088   // enc L0: [h(1024) | x(64)]
#define K1    2048   // enc L1: [h1(1024) | y0(1024)]
#define KD0   1120   // dec L0: [h(1024) | yp(32) x(64)]
#define KD1   2048   // dec L1: [h1(1024) | h0(1024)]
#define KH    1024

#define SX0  (Bsz * K0)
#define SX1  (Bsz * K1)
#define SXD0 (Bsz * KD0)
#define SXD1 (Bsz * KD1)
#define SH   (Bsz * Hdim)

// barrier layout in u32 words: leaves at i*16 (i<32), root at 512, gen at 528
#define BAR_ROOT 512
#define BAR_GEN  528
#define BAR_WORDS 544

__device__ __forceinline__ u16 f2bf(float f) {
    union { float f; unsigned u; } c; c.f = f;
    unsigned u = c.u;
    unsigned r = (u + 0x7fffu + ((u >> 16) & 1u)) >> 16;
    return (u16)r;
}

__device__ __forceinline__ f32x4 mfma16(bf16x8 a, bf16x8 b, f32x4 c) {
    return __builtin_amdgcn_mfma_f32_16x16x32_bf16(a, b, c, 0, 0, 0);
}

// ---------- agent-coherent (IF$-level) state accessors: bypass L1/L2,
// so cross-XCD state is never stale and NO cache invalidation is needed.
__device__ __forceinline__ u64 ald64(const void* p) {
    return __hip_atomic_load((const u64*)p, __ATOMIC_RELAXED, __HIP_MEMORY_SCOPE_AGENT);
}
__device__ __forceinline__ void ast64(void* p, u64 v) {
    __hip_atomic_store((u64*)p, v, __ATOMIC_RELAXED, __HIP_MEMORY_SCOPE_AGENT);
}
__device__ __forceinline__ float aldf(const float* p) {
    return __hip_atomic_load(p, __ATOMIC_RELAXED, __HIP_MEMORY_SCOPE_AGENT);
}
__device__ __forceinline__ void astf(float* p, float v) {
    __hip_atomic_store(p, v, __ATOMIC_RELAXED, __HIP_MEMORY_SCOPE_AGENT);
}
__device__ __forceinline__ u16 aldu16(const u16* p) {
    return __hip_atomic_load(p, __ATOMIC_RELAXED, __HIP_MEMORY_SCOPE_AGENT);
}
__device__ __forceinline__ void astu16(u16* p, u16 v) {
    __hip_atomic_store(p, v, __ATOMIC_RELAXED, __HIP_MEMORY_SCOPE_AGENT);
}
// 16B state load as 2x8B agent loads
__device__ __forceinline__ bf16x8 ldx(const u16* p) {
    union { u64 q[2]; bf16x8 v; } u;
    u.q[0] = ald64(p);
    u.q[1] = ald64(p + 4);
    return u.v;
}

// ---------------- software grid barrier (multi-XCD safe, no cache ops) ----
// Generation-based, hierarchical (32 leaves x 8 blocks -> root -> gen).
// All cross-block data moves through agent-scope (sc1) accesses, so the
// barrier itself needs NO L2 writeback/invalidate: just drain vmcnt and
// count arrivals with relaxed agent atomics.
__device__ __forceinline__ void gridbar(unsigned* bar, unsigned target) {
    __syncthreads();   // each wave: s_waitcnt vmcnt(0) lgkmcnt(0); s_barrier
    if (threadIdx.x == 0) {
        asm volatile("s_waitcnt vmcnt(0) lgkmcnt(0)" ::: "memory");
        unsigned leaf = (blockIdx.x >> 3) << 4;
        unsigned a = __hip_atomic_fetch_add(&bar[leaf], 1u,
                        __ATOMIC_RELAXED, __HIP_MEMORY_SCOPE_AGENT);
        if (((a + 1u) & 7u) == 0u) {
            unsigned r = __hip_atomic_fetch_add(&bar[BAR_ROOT], 1u,
                            __ATOMIC_RELAXED, __HIP_MEMORY_SCOPE_AGENT);
            if (((r + 1u) & 31u) == 0u)
                __hip_atomic_fetch_add(&bar[BAR_GEN], 1u,
                        __ATOMIC_RELAXED, __HIP_MEMORY_SCOPE_AGENT);
        }
        while (__hip_atomic_load(&bar[BAR_GEN],
                    __ATOMIC_RELAXED, __HIP_MEMORY_SCOPE_AGENT) < target)
            __builtin_amdgcn_s_sleep(2);
        asm volatile("" ::: "memory");
    }
    __syncthreads();
}

// ---------------- prologue kernels ----------------

__global__ void __launch_bounds__(256) pack2(
        const float* __restrict__ A, int KA,
        const float* __restrict__ Bs, int KB,
        u16* __restrict__ dst) {
    int row = blockIdx.y;
    int k = blockIdx.x * 256 + threadIdx.x;
    int K = KA + KB;
    if (k >= K) return;
    float v = (k < KA) ? A[(size_t)row * KA + k] : Bs[(size_t)row * KB + (k - KA)];
    dst[(size_t)row * K + k] = f2bf(v);
}

// Bias packs: [br+bhr | bz+bhz | bin | bhn] each 1024
__global__ void __launch_bounds__(256) pack_bias(
        const float* bi0e, const float* bh0e,
        const float* bi1e, const float* bh1e,
        const float* bi0d, const float* bh0d,
        const float* bi1d, const float* bh1d,
        const float* out1b,
        float* B0, float* B1, float* BD0, float* BD1, float* HB) {
    int j = blockIdx.x * blockDim.x + threadIdx.x;
    if (j >= 1024) return;
    const float* bis[4] = { bi0e, bi1e, bi0d, bi1d };
    const float* bhs[4] = { bh0e, bh1e, bh0d, bh1d };
    float* ds[4] = { B0, B1, BD0, BD1 };
#pragma unroll
    for (int s = 0; s < 4; ++s) {
        ds[s][j]        = bis[s][j]        + bhs[s][j];
        ds[s][1024 + j] = bis[s][1024 + j] + bhs[s][1024 + j];
        ds[s][2048 + j] = bis[s][2048 + j];
        ds[s][3072 + j] = bhs[s][2048 + j];
    }
    HB[j] = out1b[j];
}

__global__ void __launch_bounds__(256) init_state(
        const float* __restrict__ enc_input,
        u16* __restrict__ X0, u16* __restrict__ X1,
        float* __restrict__ H0f, float* __restrict__ H1f,
        unsigned* __restrict__ bar) {
    int gtid = blockIdx.x * blockDim.x + threadIdx.x;
    int G = gridDim.x * blockDim.x;
    for (int i = gtid; i < BAR_WORDS; i += G) bar[i] = 0u;
    for (int i = gtid; i < Bsz * Hdim; i += G) { int b = i >> 10, j = i & 1023; X0[(size_t)b * K0 + j] = 0; }
    for (int i = gtid; i < Bsz * INF; i += G) { int b = i >> 6, f = i & 63;
        X0[(size_t)b * K0 + 1024 + f] = f2bf(enc_input[(size_t)b * (TIN * INF) + f]); }
    // X1 parity1: h1-part (offset 0) = 0
    for (int i = gtid; i < Bsz * Hdim; i += G) { int b = i >> 10, j = i & 1023;
        X1[(size_t)SX1 + (size_t)b * K1 + j] = 0; }
    for (int i = gtid; i < Bsz * Hdim; i += G) { H0f[i] = 0.f; H1f[SH + i] = 0.f; }
}

// ---------------- K-split GRU wave ----------------
// W loads: plain (L2-resident, read-only). X loads: agent-coherent (state).
template <int KB0, int KB1, int SPLIT>
__device__ __forceinline__ void gru_wave(
        const u16* __restrict__ W, const u16* __restrict__ X, int K,
        int j0, int nb0w,
        f32x4& accR, f32x4& accZ, f32x4& accN0, f32x4& accN1) {
    const int lane = threadIdx.x & 63;
    const int l15 = lane & 15, kq = lane >> 4;
    const u16* Wr = W + (size_t)(j0 + l15) * K + kq * 8;
    const u16* Wz = Wr + (size_t)1024 * K;
    const u16* Wn = Wz + (size_t)1024 * K;
    const u16* Xb = X + (size_t)(nb0w + l15) * K + kq * 8;
    accR = (f32x4){0.f, 0.f, 0.f, 0.f};
    accZ = (f32x4){0.f, 0.f, 0.f, 0.f};
    accN0 = (f32x4){0.f, 0.f, 0.f, 0.f};
    accN1 = (f32x4){0.f, 0.f, 0.f, 0.f};
    constexpr int E0 = (SPLIT < KB1) ? SPLIT : KB1;
    constexpr int S1 = (SPLIT > KB0) ? SPLIT : KB0;
#pragma unroll 8
    for (int kb = KB0; kb < E0; ++kb) {
        const int o = kb * 32;
        bf16x8 xb = ldx(Xb + o);
        accR  = mfma16(*(const bf16x8*)(Wr + o), xb, accR);
        accZ  = mfma16(*(const bf16x8*)(Wz + o), xb, accZ);
        accN0 = mfma16(*(const bf16x8*)(Wn + o), xb, accN0);
    }
#pragma unroll 8
    for (int kb = S1; kb < KB1; ++kb) {
        const int o = kb * 32;
        bf16x8 xb = ldx(Xb + o);
        accR  = mfma16(*(const bf16x8*)(Wr + o), xb, accR);
        accZ  = mfma16(*(const bf16x8*)(Wz + o), xb, accZ);
        accN1 = mfma16(*(const bf16x8*)(Wn + o), xb, accN1);
    }
}

// ---------------- WG-level GRU tile: 16 h-rows x 64 batch, K split over 2
// wave groups (waves 0-3 = kb [0,MID), waves 4-7 = kb [MID,KBT)), LDS combine.
template <int KBT, int SPLIT>
__device__ __forceinline__ void gru_block(
        const u16* __restrict__ W, const u16* __restrict__ X,
        const float* __restrict__ Hold, const float* __restrict__ Bias,
        int K, int ct, int nb0,
        float* __restrict__ Hnew,
        u16* __restrict__ O1, int ld1, int off1,
        u16* __restrict__ O2, int ld2, int off2,
        float* __restrict__ sred /* [4][64][17] */) {
    const int tid = threadIdx.x, lane = tid & 63, w = tid >> 6;
    const int bg = w & 3, grp = w >> 2;
    const int l15 = lane & 15, kq = lane >> 4;
    const int j0 = ct * 16;
    const int nb0w = nb0 + bg * 16;
    constexpr int MID = KBT / 2;

    f32x4 aR, aZ, aN0, aN1;
    if (grp == 0) gru_wave<0, MID, SPLIT>(W, X, K, j0, nb0w, aR, aZ, aN0, aN1);
    else          gru_wave<MID, KBT, SPLIT>(W, X, K, j0, nb0w, aR, aZ, aN0, aN1);

    float* slot = sred + ((size_t)bg * 64 + lane) * 17;
    if (grp == 1) {
#pragma unroll
        for (int q = 0; q < 4; ++q) {
            slot[q]      = aR[q];
            slot[4 + q]  = aZ[q];
            slot[8 + q]  = aN0[q];
            slot[12 + q] = aN1[q];
        }
    }
    __syncthreads();
    if (grp == 0) {
        const int nb = nb0w + l15;
        float hv4[4];
#pragma unroll
        for (int q = 0; q < 4; ++q) {
            const int j = j0 + kq * 4 + q;
            float R  = aR[q]  + slot[q];
            float Z  = aZ[q]  + slot[4 + q];
            float Nh = aN0[q] + slot[8 + q];
            float Ni = aN1[q] + slot[12 + q];
            float r = 1.f / (1.f + expf(-(R + Bias[j])));
            float z = 1.f / (1.f + expf(-(Z + Bias[1024 + j])));
            float n = tanhf(Ni + Bias[2048 + j] + r * (Nh + Bias[3072 + j]));
            float ho = aldf(&Hold[(size_t)j * Bsz + nb]);
            float hv = (1.f - z) * n + z * ho;
            astf(&Hnew[(size_t)j * Bsz + nb], hv);
            hv4[q] = hv;
        }
        union { u16 h[4]; u64 q8; } pk;
#pragma unroll
        for (int q = 0; q < 4; ++q) pk.h[q] = f2bf(hv4[q]);
        ast64(&O1[(size_t)nb * ld1 + off1 + j0 + kq * 4], pk.q8);
        if (O2) ast64(&O2[(size_t)nb * ld2 + off2 + j0 + kq * 4], pk.q8);
    }
}

// ---------------- params ----------------
struct KParams {
    const float* enc_input;
    const float* dec_input;
    const u16 *W0, *W1, *WD0, *WD1, *WH1, *WH2;
    const float *B0, *B1, *BD0, *BD1, *HB;
    u16 *X0, *X1, *XD0, *XD1, *Hhead, *Abuf;
    float *H0f, *H1f;
    float* out;
    unsigned* bar;
};

// ---------------- round bodies (device functions) ----------------

__device__ __forceinline__ void enc_round_body(const KParams& p, int r, float* sred) {
    const int wg = blockIdx.x;
    const int pr = r & 1, pw = pr ^ 1;
    if (wg < 128) {
        if (r < 512) {
            gru_block<34, 32>(p.W0, p.X0 + pr * SX0, p.H0f + pr * SH, p.B0,
                              K0, wg >> 1, (wg & 1) * 64,
                              p.H0f + pw * SH,
                              p.X0 + pw * SX0, K0, 0,
                              p.X1 + pw * SX1, K1, 1024, sred);
            if (r + 1 < 512 && threadIdx.x < 16) {
                int b = wg, f4 = threadIdx.x * 4;
                const float* src = p.enc_input + ((size_t)b * TIN + (r + 1)) * INF + f4;
                union { u16 h[4]; u64 q8; } pk;
#pragma unroll
                for (int i = 0; i < 4; ++i) pk.h[i] = f2bf(src[i]);
                ast64(&p.X0[(size_t)pw * SX0 + (size_t)b * K0 + 1024 + f4], pk.q8);
            }
        }
    } else {
        if (r >= 1) {
            int w2 = wg - 128;
            gru_block<64, 32>(p.W1, p.X1 + pr * SX1, p.H1f + pr * SH, p.B1,
                              K1, w2 >> 1, (w2 & 1) * 64,
                              p.H1f + pw * SH,
                              p.X1 + pw * SX1, K1, 0,
                              (u16*)nullptr, 0, 0, sred);
        }
    }
}

__device__ __forceinline__ void transition_body(const KParams& p) {
    int gtid = blockIdx.x * blockDim.x + threadIdx.x;
    const int G = 256 * 512;
    for (int i = gtid; i < SH; i += G)
        astf(&p.H1f[i], aldf(&p.H1f[SH + i]));
    for (int i = gtid; i < Bsz * Hdim; i += G) {
        int b = i >> 10, j = i & 1023;
        astu16(&p.XD0[(size_t)b * KD0 + j], aldu16(&p.X0[(size_t)b * K0 + j]));  // eh0 bf16
    }
    for (int i = gtid; i < Bsz * OUTF; i += G) {
        int b = i >> 5, f = i & 31;
        astu16(&p.XD0[(size_t)b * KD0 + 1024 + f],
               f2bf(p.enc_input[((size_t)b * TIN + (TIN - 1)) * INF + f]));
    }
    for (int i = gtid; i < Bsz * INF; i += G) {
        int b = i >> 6, f = i & 63;
        astu16(&p.XD0[(size_t)b * KD0 + 1056 + f],
               f2bf(p.dec_input[(size_t)b * (TOUT * INF) + f]));
    }
    for (int i = gtid; i < Bsz * Hdim; i += G) {
        int b = i >> 10, j = i & 1023;
        astu16(&p.XD1[(size_t)b * KD1 + j],
               aldu16(&p.X1[(size_t)SX1 + (size_t)b * K1 + j]));  // eh1 bf16
    }
}

__device__ __forceinline__ void dec_A_body(const KParams& p, int t, float* sred) {
    const int wg = blockIdx.x;
    const int pt = t & 1, pn = pt ^ 1;
    gru_block<35, 32>(p.WD0, p.XD0 + pt * SXD0, p.H0f + pt * SH, p.BD0,
                      KD0, wg >> 1, (wg & 1) * 64,
                      p.H0f + pn * SH,
                      p.XD0 + pn * SXD0, KD0, 0,
                      p.XD1 + pt * SXD1, KD1, 1024, sred);
}

__device__ __forceinline__ void dec_B_body(const KParams& p, int t, float* sred) {
    const int wg = blockIdx.x;
    const int pt = t & 1, pn = pt ^ 1;
    gru_block<64, 32>(p.WD1, p.XD1 + pt * SXD1, p.H1f + pt * SH, p.BD1,
                      KD1, wg >> 1, (wg & 1) * 64,
                      p.H1f + pn * SH,
                      p.XD1 + pn * SXD1, KD1, 0,
                      p.Hhead, KH, 0, sred);
}

// a = relu(h1 @ W1^T + b); also stage x_{t+1}. waves 0-3 active.
__device__ __forceinline__ void dec_C_body(const KParams& p, int t) {
    const int wg = blockIdx.x;
    const int pn = (t & 1) ^ 1;
    const int tid = threadIdx.x, lane = tid & 63, w = tid >> 6;
    if (w < 4) {
        const int l15 = lane & 15, kq = lane >> 4;
        const int ct = wg >> 1, nb0 = (wg & 1) * 64;
        const int j0 = ct * 16;
        const int nb = nb0 + w * 16 + l15;
        const u16* Wr = p.WH1 + (size_t)(j0 + l15) * KH + kq * 8;
        const u16* Xb = p.Hhead + (size_t)nb * KH + kq * 8;
        f32x4 acc = {0.f, 0.f, 0.f, 0.f};
#pragma unroll 8
        for (int kb = 0; kb < KH / 32; ++kb) {
            const int o = kb * 32;
            acc = mfma16(*(const bf16x8*)(Wr + o), ldx(Xb + o), acc);
        }
        union { u16 h[4]; u64 q8; } pk;
#pragma unroll
        for (int q = 0; q < 4; ++q) {
            const int j = j0 + kq * 4 + q;
            float v = acc[q] + p.HB[j];
            pk.h[q] = f2bf(v > 0.f ? v : 0.f);
        }
        ast64(&p.Abuf[(size_t)nb * KH + j0 + kq * 4], pk.q8);
        if (t + 1 < TOUT && tid < 16) {
            int b = wg, f4 = tid * 4;
            const float* src = p.dec_input + ((size_t)b * TOUT + (t + 1)) * INF + f4;
            union { u16 h[4]; u64 q8; } pk2;
#pragma unroll
            for (int i = 0; i < 4; ++i) pk2.h[i] = f2bf(src[i]);
            ast64(&p.XD0[(size_t)pn * SXD0 + (size_t)b * KD0 + 1056 + f4], pk2.q8);
        }
    }
}

// out = a @ W2^T (32 x 128), blocks 0-15, waves 0-3 split K, LDS-reduce.
__device__ __forceinline__ void dec_D_body(const KParams& p, int t, float* sred) {
    const int wg = blockIdx.x;
    const int pn = (t & 1) ^ 1;
    const int tid = threadIdx.x, lane = tid & 63, w = tid >> 6;
    const int l15 = lane & 15, kq = lane >> 4;
    const int mt = wg & 1, nt = wg >> 1;
    if (w < 4) {
        const u16* Wr = p.WH2 + (size_t)(mt * 16 + l15) * KH + kq * 8;
        const u16* Xb = p.Abuf + (size_t)(nt * 16 + l15) * KH + kq * 8;
        f32x4 acc = {0.f, 0.f, 0.f, 0.f};
#pragma unroll 8
        for (int kb = w * 8; kb < w * 8 + 8; ++kb) {
            const int o = kb * 32;
            acc = mfma16(*(const bf16x8*)(Wr + o), ldx(Xb + o), acc);
        }
#pragma unroll
        for (int q = 0; q < 4; ++q) sred[(w * 64 + lane) * 4 + q] = acc[q];
    }
    __syncthreads();
    if (w == 0) {
        int b = nt * 16 + l15;
        union { u16 h[4]; u64 q8; } pk;
#pragma unroll
        for (int q = 0; q < 4; ++q) {
            float s = sred[(0 * 64 + lane) * 4 + q] + sred[(1 * 64 + lane) * 4 + q] +
                      sred[(2 * 64 + lane) * 4 + q] + sred[(3 * 64 + lane) * 4 + q];
            int feat = mt * 16 + kq * 4 + q;
            p.out[(size_t)b * (TOUT * OUTF) + t * OUTF + feat] = s;
            pk.h[q] = f2bf(s);
        }
        ast64(&p.XD0[(size_t)pn * SXD0 + (size_t)b * KD0 + 1024 + mt * 16 + kq * 4], pk.q8);
    }
}

// ---------------- the persistent kernel ----------------
__global__ void __launch_bounds__(512, 1) seq2seq_persist(KParams p) {
    __shared__ float sred[4 * 64 * 17];
    unsigned target = 0;

    // encoder: 513 pipelined rounds
    for (int r = 0; r < 513; ++r) {
        enc_round_body(p, r, sred);
        gridbar(p.bar, ++target);
    }

    // transition
    transition_body(p);
    gridbar(p.bar, ++target);

    // decoder: 64 steps x 4 rounds
    for (int t = 0; t < TOUT; ++t) {
        if (blockIdx.x < 128) dec_A_body(p, t, sred);
        gridbar(p.bar, ++target);
        if (blockIdx.x < 128) dec_B_body(p, t, sred);
        gridbar(p.bar, ++target);
        if (blockIdx.x < 128) dec_C_body(p, t);
        gridbar(p.bar, ++target);
        if (blockIdx.x < 16) dec_D_body(p, t, sred);
        if (t + 1 < TOUT) gridbar(p.bar, ++target);
    }
}

// ---------------- host launch ----------------
extern "C" void kernel_launch(void* const* d_in, const int* in_sizes, int n_in,
                              void* d_out, int out_size, void* d_ws, size_t ws_size,
                              hipStream_t stream) {
    const float* enc_input = (const float*)d_in[0];
    const float* dec_input = (const float*)d_in[1];
    const float* enc_Wih0 = (const float*)d_in[2];
    const float* enc_Whh0 = (const float*)d_in[3];
    const float* enc_bih0 = (const float*)d_in[4];
    const float* enc_bhh0 = (const float*)d_in[5];
    const float* enc_Wih1 = (const float*)d_in[6];
    const float* enc_Whh1 = (const float*)d_in[7];
    const float* enc_bih1 = (const float*)d_in[8];
    const float* enc_bhh1 = (const float*)d_in[9];
    const float* dec_Wih0 = (const float*)d_in[10];
    const float* dec_Whh0 = (const float*)d_in[11];
    const float* dec_bih0 = (const float*)d_in[12];
    const float* dec_bhh0 = (const float*)d_in[13];
    const float* dec_Wih1 = (const float*)d_in[14];
    const float* dec_Whh1 = (const float*)d_in[15];
    const float* dec_bih1 = (const float*)d_in[16];
    const float* dec_bhh1 = (const float*)d_in[17];
    const float* out1_W = (const float*)d_in[18];
    const float* out1_b = (const float*)d_in[19];
    const float* out2_W = (const float*)d_in[20];

    char* ws = (char*)d_ws;
    size_t off = 0;
    auto alloc = [&](size_t bytes) { size_t o = off; off = (off + bytes + 255) & ~(size_t)255; return o; };

    u16* W0 = (u16*)(ws + alloc((size_t)H3 * K0 * 2));
    u16* W1 = (u16*)(ws + alloc((size_t)H3 * K1 * 2));
    u16* WD0 = (u16*)(ws + alloc((size_t)H3 * KD0 * 2));
    u16* WD1 = (u16*)(ws + alloc((size_t)H3 * KD1 * 2));
    u16* WH1 = (u16*)(ws + alloc((size_t)Hdim * KH * 2));
    u16* WH2 = (u16*)(ws + alloc((size_t)OUTF * KH * 2));
    float* B0 = (float*)(ws + alloc(4096 * 4));
    float* B1 = (float*)(ws + alloc(4096 * 4));
    float* BD0 = (float*)(ws + alloc(4096 * 4));
    float* BD1 = (float*)(ws + alloc(4096 * 4));
    float* HB = (float*)(ws + alloc(1024 * 4));
    u16* X0 = (u16*)(ws + alloc((size_t)2 * Bsz * K0 * 2));
    u16* X1 = (u16*)(ws + alloc((size_t)2 * Bsz * K1 * 2));
    u16* XD0 = (u16*)(ws + alloc((size_t)2 * Bsz * KD0 * 2));
    u16* XD1 = (u16*)(ws + alloc((size_t)2 * Bsz * KD1 * 2));
    float* H0f = (float*)(ws + alloc((size_t)2 * Bsz * Hdim * 4));
    float* H1f = (float*)(ws + alloc((size_t)2 * Bsz * Hdim * 4));
    u16* Hhead = (u16*)(ws + alloc((size_t)Bsz * KH * 2));
    u16* Abuf = (u16*)(ws + alloc((size_t)Bsz * KH * 2));
    unsigned* bar = (unsigned*)(ws + alloc(BAR_WORDS * 4));

    // --- prologue: weight/bias repack (h-part FIRST) + state/barrier init ---
    pack2<<<dim3((K0 + 255) / 256, H3), 256, 0, stream>>>(enc_Whh0, 1024, enc_Wih0, 64, W0);
    pack2<<<dim3((K1 + 255) / 256, H3), 256, 0, stream>>>(enc_Whh1, 1024, enc_Wih1, 1024, W1);
    pack2<<<dim3((KD0 + 255) / 256, H3), 256, 0, stream>>>(dec_Whh0, 1024, dec_Wih0, 96, WD0);
    pack2<<<dim3((KD1 + 255) / 256, H3), 256, 0, stream>>>(dec_Whh1, 1024, dec_Wih1, 1024, WD1);
    pack2<<<dim3((KH + 255) / 256, Hdim), 256, 0, stream>>>(out1_W, 1024, nullptr, 0, WH1);
    pack2<<<dim3((KH + 255) / 256, OUTF), 256, 0, stream>>>(out2_W, 1024, nullptr, 0, WH2);
    pack_bias<<<4, 256, 0, stream>>>(enc_bih0, enc_bhh0, enc_bih1, enc_bhh1,
                                     dec_bih0, dec_bhh0, dec_bih1, dec_bhh1,
                                     out1_b, B0, B1, BD0, BD1, HB);
    init_state<<<256, 256, 0, stream>>>(enc_input, X0, X1, H0f, H1f, bar);

    KParams kp;
    kp.enc_input = enc_input; kp.dec_input = dec_input;
    kp.W0 = W0; kp.W1 = W1; kp.WD0 = WD0; kp.WD1 = WD1; kp.WH1 = WH1; kp.WH2 = WH2;
    kp.B0 = B0; kp.B1 = B1; kp.BD0 = BD0; kp.BD1 = BD1; kp.HB = HB;
    kp.X0 = X0; kp.X1 = X1; kp.XD0 = XD0; kp.XD1 = XD1; kp.Hhead = Hhead; kp.Abuf = Abuf;
    kp.H0f = H0f; kp.H1f = H1f;
    kp.out = (float*)d_out;
    kp.bar = bar;

    // --- one persistent kernel: software grid barrier between rounds ---
    seq2seq_persist<<<256, 512, 0, stream>>>(kp);
}

// Round 6
// 29538.568 us; speedup vs baseline: 2.0570x; 1.0098x over previous
//
#include <hip/hip_runtime.h>

typedef unsigned short u16;
typedef unsigned long long u64;
typedef __attribute__((ext_vector_type(8))) short bf16x8;
typedef __attribute__((ext_vector_type(4))) float f32x4;

// ---------------- constants ----------------
#define Bsz   128
#define TIN   512
#define TOUT  64
#define INF   64
#define OUTF  32
#define Hdim  1024
#define H3    3072

// K layouts: H-PART FIRST everywhere (uniform n-gate split at kb=32)
#define K0    1088   // enc L0: [h(1024) | x(64)]
#define K1    2048   // enc L1: [h1(1024) | y0(1024)]
#define KD0   1120   // dec L0: [h(1024) | yp(32) x(64)]
#define KD1   2048   // dec L1: [h1(1024) | h0(1024)]
#define KH    1024

#define SX0  (Bsz * K0)
#define SX1  (Bsz * K1)
#define SXD0 (Bsz * KD0)
#define SXD1 (Bsz * KD1)
#define SH   (Bsz * Hdim)

// barrier layout in u32 words: leaves at i*16 (i<32), root at 512, gen at 528
#define BAR_ROOT 512
#define BAR_GEN  528
#define BAR_WORDS 544

__device__ __forceinline__ u16 f2bf(float f) {
    union { float f; unsigned u; } c; c.f = f;
    unsigned u = c.u;
    unsigned r = (u + 0x7fffu + ((u >> 16) & 1u)) >> 16;
    return (u16)r;
}

__device__ __forceinline__ f32x4 mfma16(bf16x8 a, bf16x8 b, f32x4 c) {
    return __builtin_amdgcn_mfma_f32_16x16x32_bf16(a, b, c, 0, 0, 0);
}

// XCD-aware tile map: blocks with equal (wg % 8) land on the same XCD
// (round-robin dispatch). Map wg(0..127) -> 64 tiles x 2 batch-halves such
// that (a) both halves of a tile share an XCD, (b) each XCD reads a disjoint
// 1/8 of the weight rows -> per-XCD weight working set ~2.4 MB < 4 MiB L2.
__device__ __forceinline__ void tile_map(int wg, int& ct, int& nb0) {
    const int xcd = wg & 7, idx = wg >> 3;
    ct = ((idx & 7) << 3) + xcd;
    nb0 = (idx >> 3) * 64;
}

// ---------- agent-coherent (IF$-level) state accessors: bypass L1/L2,
// so cross-XCD state is never stale and NO cache invalidation is needed.
__device__ __forceinline__ u64 ald64(const void* p) {
    return __hip_atomic_load((const u64*)p, __ATOMIC_RELAXED, __HIP_MEMORY_SCOPE_AGENT);
}
__device__ __forceinline__ void ast64(void* p, u64 v) {
    __hip_atomic_store((u64*)p, v, __ATOMIC_RELAXED, __HIP_MEMORY_SCOPE_AGENT);
}
__device__ __forceinline__ float aldf(const float* p) {
    return __hip_atomic_load(p, __ATOMIC_RELAXED, __HIP_MEMORY_SCOPE_AGENT);
}
__device__ __forceinline__ void astf(float* p, float v) {
    __hip_atomic_store(p, v, __ATOMIC_RELAXED, __HIP_MEMORY_SCOPE_AGENT);
}
__device__ __forceinline__ u16 aldu16(const u16* p) {
    return __hip_atomic_load(p, __ATOMIC_RELAXED, __HIP_MEMORY_SCOPE_AGENT);
}
__device__ __forceinline__ void astu16(u16* p, u16 v) {
    __hip_atomic_store(p, v, __ATOMIC_RELAXED, __HIP_MEMORY_SCOPE_AGENT);
}
// 16B state load as 2x8B agent loads
__device__ __forceinline__ bf16x8 ldx(const u16* p) {
    union { u64 q[2]; bf16x8 v; } u;
    u.q[0] = ald64(p);
    u.q[1] = ald64(p + 4);
    return u.v;
}

// ---------------- software grid barrier (multi-XCD safe, no cache ops) ----
__device__ __forceinline__ void gridbar(unsigned* bar, unsigned target) {
    __syncthreads();
    if (threadIdx.x == 0) {
        asm volatile("s_waitcnt vmcnt(0) lgkmcnt(0)" ::: "memory");
        unsigned leaf = (blockIdx.x >> 3) << 4;
        unsigned a = __hip_atomic_fetch_add(&bar[leaf], 1u,
                        __ATOMIC_RELAXED, __HIP_MEMORY_SCOPE_AGENT);
        if (((a + 1u) & 7u) == 0u) {
            unsigned r = __hip_atomic_fetch_add(&bar[BAR_ROOT], 1u,
                            __ATOMIC_RELAXED, __HIP_MEMORY_SCOPE_AGENT);
            if (((r + 1u) & 31u) == 0u)
                __hip_atomic_fetch_add(&bar[BAR_GEN], 1u,
                        __ATOMIC_RELAXED, __HIP_MEMORY_SCOPE_AGENT);
        }
        while (__hip_atomic_load(&bar[BAR_GEN],
                    __ATOMIC_RELAXED, __HIP_MEMORY_SCOPE_AGENT) < target)
            __builtin_amdgcn_s_sleep(2);
        asm volatile("" ::: "memory");
    }
    __syncthreads();
}

// ---------------- prologue kernels ----------------

__global__ void __launch_bounds__(256) pack2(
        const float* __restrict__ A, int KA,
        const float* __restrict__ Bs, int KB,
        u16* __restrict__ dst) {
    int row = blockIdx.y;
    int k = blockIdx.x * 256 + threadIdx.x;
    int K = KA + KB;
    if (k >= K) return;
    float v = (k < KA) ? A[(size_t)row * KA + k] : Bs[(size_t)row * KB + (k - KA)];
    dst[(size_t)row * K + k] = f2bf(v);
}

// Bias packs: [br+bhr | bz+bhz | bin | bhn] each 1024
__global__ void __launch_bounds__(256) pack_bias(
        const float* bi0e, const float* bh0e,
        const float* bi1e, const float* bh1e,
        const float* bi0d, const float* bh0d,
        const float* bi1d, const float* bh1d,
        const float* out1b,
        float* B0, float* B1, float* BD0, float* BD1, float* HB) {
    int j = blockIdx.x * blockDim.x + threadIdx.x;
    if (j >= 1024) return;
    const float* bis[4] = { bi0e, bi1e, bi0d, bi1d };
    const float* bhs[4] = { bh0e, bh1e, bh0d, bh1d };
    float* ds[4] = { B0, B1, BD0, BD1 };
#pragma unroll
    for (int s = 0; s < 4; ++s) {
        ds[s][j]        = bis[s][j]        + bhs[s][j];
        ds[s][1024 + j] = bis[s][1024 + j] + bhs[s][1024 + j];
        ds[s][2048 + j] = bis[s][2048 + j];
        ds[s][3072 + j] = bhs[s][2048 + j];
    }
    HB[j] = out1b[j];
}

__global__ void __launch_bounds__(256) init_state(
        const float* __restrict__ enc_input,
        u16* __restrict__ X0, u16* __restrict__ X1,
        float* __restrict__ H0f, float* __restrict__ H1f,
        unsigned* __restrict__ bar) {
    int gtid = blockIdx.x * blockDim.x + threadIdx.x;
    int G = gridDim.x * blockDim.x;
    for (int i = gtid; i < BAR_WORDS; i += G) bar[i] = 0u;
    for (int i = gtid; i < Bsz * Hdim; i += G) { int b = i >> 10, j = i & 1023; X0[(size_t)b * K0 + j] = 0; }
    for (int i = gtid; i < Bsz * INF; i += G) { int b = i >> 6, f = i & 63;
        X0[(size_t)b * K0 + 1024 + f] = f2bf(enc_input[(size_t)b * (TIN * INF) + f]); }
    // X1 parity1: h1-part (offset 0) = 0
    for (int i = gtid; i < Bsz * Hdim; i += G) { int b = i >> 10, j = i & 1023;
        X1[(size_t)SX1 + (size_t)b * K1 + j] = 0; }
    for (int i = gtid; i < Bsz * Hdim; i += G) { H0f[i] = 0.f; H1f[SH + i] = 0.f; }
}

// ---------------- K-split GRU wave ----------------
// W loads: plain (L2-resident, read-only). X loads: agent-coherent (state).
template <int KB0, int KB1, int SPLIT>
__device__ __forceinline__ void gru_wave(
        const u16* __restrict__ W, const u16* __restrict__ X, int K,
        int j0, int nb0w,
        f32x4& accR, f32x4& accZ, f32x4& accN0, f32x4& accN1) {
    const int lane = threadIdx.x & 63;
    const int l15 = lane & 15, kq = lane >> 4;
    const u16* Wr = W + (size_t)(j0 + l15) * K + kq * 8;
    const u16* Wz = Wr + (size_t)1024 * K;
    const u16* Wn = Wz + (size_t)1024 * K;
    const u16* Xb = X + (size_t)(nb0w + l15) * K + kq * 8;
    accR = (f32x4){0.f, 0.f, 0.f, 0.f};
    accZ = (f32x4){0.f, 0.f, 0.f, 0.f};
    accN0 = (f32x4){0.f, 0.f, 0.f, 0.f};
    accN1 = (f32x4){0.f, 0.f, 0.f, 0.f};
    constexpr int E0 = (SPLIT < KB1) ? SPLIT : KB1;
    constexpr int S1 = (SPLIT > KB0) ? SPLIT : KB0;
#pragma unroll 8
    for (int kb = KB0; kb < E0; ++kb) {
        const int o = kb * 32;
        bf16x8 xb = ldx(Xb + o);
        accR  = mfma16(*(const bf16x8*)(Wr + o), xb, accR);
        accZ  = mfma16(*(const bf16x8*)(Wz + o), xb, accZ);
        accN0 = mfma16(*(const bf16x8*)(Wn + o), xb, accN0);
    }
#pragma unroll 8
    for (int kb = S1; kb < KB1; ++kb) {
        const int o = kb * 32;
        bf16x8 xb = ldx(Xb + o);
        accR  = mfma16(*(const bf16x8*)(Wr + o), xb, accR);
        accZ  = mfma16(*(const bf16x8*)(Wz + o), xb, accZ);
        accN1 = mfma16(*(const bf16x8*)(Wn + o), xb, accN1);
    }
}

// ---------------- WG-level GRU tile: 16 h-rows x 64 batch, K split over 2
// wave groups (waves 0-3 = kb [0,MID), waves 4-7 = kb [MID,KBT)), LDS combine.
template <int KBT, int SPLIT>
__device__ __forceinline__ void gru_block(
        const u16* __restrict__ W, const u16* __restrict__ X,
        const float* __restrict__ Hold, const float* __restrict__ Bias,
        int K, int ct, int nb0,
        float* __restrict__ Hnew,
        u16* __restrict__ O1, int ld1, int off1,
        u16* __restrict__ O2, int ld2, int off2,
        float* __restrict__ sred /* [4][64][17] */) {
    const int tid = threadIdx.x, lane = tid & 63, w = tid >> 6;
    const int bg = w & 3, grp = w >> 2;
    const int l15 = lane & 15, kq = lane >> 4;
    const int j0 = ct * 16;
    const int nb0w = nb0 + bg * 16;
    constexpr int MID = KBT / 2;

    f32x4 aR, aZ, aN0, aN1;
    if (grp == 0) gru_wave<0, MID, SPLIT>(W, X, K, j0, nb0w, aR, aZ, aN0, aN1);
    else          gru_wave<MID, KBT, SPLIT>(W, X, K, j0, nb0w, aR, aZ, aN0, aN1);

    float* slot = sred + ((size_t)bg * 64 + lane) * 17;
    if (grp == 1) {
#pragma unroll
        for (int q = 0; q < 4; ++q) {
            slot[q]      = aR[q];
            slot[4 + q]  = aZ[q];
            slot[8 + q]  = aN0[q];
            slot[12 + q] = aN1[q];
        }
    }
    __syncthreads();
    if (grp == 0) {
        const int nb = nb0w + l15;
        float hv4[4];
#pragma unroll
        for (int q = 0; q < 4; ++q) {
            const int j = j0 + kq * 4 + q;
            float R  = aR[q]  + slot[q];
            float Z  = aZ[q]  + slot[4 + q];
            float Nh = aN0[q] + slot[8 + q];
            float Ni = aN1[q] + slot[12 + q];
            float r = 1.f / (1.f + expf(-(R + Bias[j])));
            float z = 1.f / (1.f + expf(-(Z + Bias[1024 + j])));
            float n = tanhf(Ni + Bias[2048 + j] + r * (Nh + Bias[3072 + j]));
            float ho = aldf(&Hold[(size_t)j * Bsz + nb]);
            float hv = (1.f - z) * n + z * ho;
            astf(&Hnew[(size_t)j * Bsz + nb], hv);
            hv4[q] = hv;
        }
        union { u16 h[4]; u64 q8; } pk;
#pragma unroll
        for (int q = 0; q < 4; ++q) pk.h[q] = f2bf(hv4[q]);
        ast64(&O1[(size_t)nb * ld1 + off1 + j0 + kq * 4], pk.q8);
        if (O2) ast64(&O2[(size_t)nb * ld2 + off2 + j0 + kq * 4], pk.q8);
    }
}

// ---------------- params ----------------
struct KParams {
    const float* enc_input;
    const float* dec_input;
    const u16 *W0, *W1, *WD0, *WD1, *WH1, *WH2;
    const float *B0, *B1, *BD0, *BD1, *HB;
    u16 *X0, *X1, *XD0, *XD1, *Hhead, *Abuf;
    float *H0f, *H1f;
    float* out;
    unsigned* bar;
};

// ---------------- round bodies (device functions) ----------------

__device__ __forceinline__ void enc_round_body(const KParams& p, int r, float* sred) {
    const int wg = blockIdx.x;
    const int pr = r & 1, pw = pr ^ 1;
    if (wg < 128) {
        if (r < 512) {
            int ct, nb0; tile_map(wg, ct, nb0);
            gru_block<34, 32>(p.W0, p.X0 + pr * SX0, p.H0f + pr * SH, p.B0,
                              K0, ct, nb0,
                              p.H0f + pw * SH,
                              p.X0 + pw * SX0, K0, 0,
                              p.X1 + pw * SX1, K1, 1024, sred);
            if (r + 1 < 512 && threadIdx.x < 16) {
                int b = wg, f4 = threadIdx.x * 4;
                const float* src = p.enc_input + ((size_t)b * TIN + (r + 1)) * INF + f4;
                union { u16 h[4]; u64 q8; } pk;
#pragma unroll
                for (int i = 0; i < 4; ++i) pk.h[i] = f2bf(src[i]);
                ast64(&p.X0[(size_t)pw * SX0 + (size_t)b * K0 + 1024 + f4], pk.q8);
            }
        }
    } else {
        if (r >= 1) {
            int ct, nb0; tile_map(wg - 128, ct, nb0);
            gru_block<64, 32>(p.W1, p.X1 + pr * SX1, p.H1f + pr * SH, p.B1,
                              K1, ct, nb0,
                              p.H1f + pw * SH,
                              p.X1 + pw * SX1, K1, 0,
                              (u16*)nullptr, 0, 0, sred);
        }
    }
}

__device__ __forceinline__ void transition_body(const KParams& p) {
    int gtid = blockIdx.x * blockDim.x + threadIdx.x;
    const int G = 256 * 512;
    for (int i = gtid; i < SH; i += G)
        astf(&p.H1f[i], aldf(&p.H1f[SH + i]));
    for (int i = gtid; i < Bsz * Hdim; i += G) {
        int b = i >> 10, j = i & 1023;
        astu16(&p.XD0[(size_t)b * KD0 + j], aldu16(&p.X0[(size_t)b * K0 + j]));  // eh0 bf16
    }
    for (int i = gtid; i < Bsz * OUTF; i += G) {
        int b = i >> 5, f = i & 31;
        astu16(&p.XD0[(size_t)b * KD0 + 1024 + f],
               f2bf(p.enc_input[((size_t)b * TIN + (TIN - 1)) * INF + f]));
    }
    for (int i = gtid; i < Bsz * INF; i += G) {
        int b = i >> 6, f = i & 63;
        astu16(&p.XD0[(size_t)b * KD0 + 1056 + f],
               f2bf(p.dec_input[(size_t)b * (TOUT * INF) + f]));
    }
    for (int i = gtid; i < Bsz * Hdim; i += G) {
        int b = i >> 10, j = i & 1023;
        astu16(&p.XD1[(size_t)b * KD1 + j],
               aldu16(&p.X1[(size_t)SX1 + (size_t)b * K1 + j]));  // eh1 bf16
    }
}

__device__ __forceinline__ void dec_A_body(const KParams& p, int t, float* sred) {
    const int wg = blockIdx.x;
    const int pt = t & 1, pn = pt ^ 1;
    int ct, nb0; tile_map(wg, ct, nb0);
    gru_block<35, 32>(p.WD0, p.XD0 + pt * SXD0, p.H0f + pt * SH, p.BD0,
                      KD0, ct, nb0,
                      p.H0f + pn * SH,
                      p.XD0 + pn * SXD0, KD0, 0,
                      p.XD1 + pt * SXD1, KD1, 1024, sred);
}

__device__ __forceinline__ void dec_B_body(const KParams& p, int t, float* sred) {
    const int wg = blockIdx.x;
    const int pt = t & 1, pn = pt ^ 1;
    int ct, nb0; tile_map(wg, ct, nb0);
    gru_block<64, 32>(p.WD1, p.XD1 + pt * SXD1, p.H1f + pt * SH, p.BD1,
                      KD1, ct, nb0,
                      p.H1f + pn * SH,
                      p.XD1 + pn * SXD1, KD1, 0,
                      p.Hhead, KH, 0, sred);
}

// a = relu(h1 @ W1^T + b); also stage x_{t+1}. waves 0-3 active.
__device__ __forceinline__ void dec_C_body(const KParams& p, int t) {
    const int wg = blockIdx.x;
    const int pn = (t & 1) ^ 1;
    const int tid = threadIdx.x, lane = tid & 63, w = tid >> 6;
    if (w < 4) {
        const int l15 = lane & 15, kq = lane >> 4;
        int ct, nb0; tile_map(wg, ct, nb0);
        const int j0 = ct * 16;
        const int nb = nb0 + w * 16 + l15;
        const u16* Wr = p.WH1 + (size_t)(j0 + l15) * KH + kq * 8;
        const u16* Xb = p.Hhead + (size_t)nb * KH + kq * 8;
        f32x4 acc = {0.f, 0.f, 0.f, 0.f};
#pragma unroll 8
        for (int kb = 0; kb < KH / 32; ++kb) {
            const int o = kb * 32;
            acc = mfma16(*(const bf16x8*)(Wr + o), ldx(Xb + o), acc);
        }
        union { u16 h[4]; u64 q8; } pk;
#pragma unroll
        for (int q = 0; q < 4; ++q) {
            const int j = j0 + kq * 4 + q;
            float v = acc[q] + p.HB[j];
            pk.h[q] = f2bf(v > 0.f ? v : 0.f);
        }
        ast64(&p.Abuf[(size_t)nb * KH + j0 + kq * 4], pk.q8);
        if (t + 1 < TOUT && tid < 16) {
            int b = wg, f4 = tid * 4;
            const float* src = p.dec_input + ((size_t)b * TOUT + (t + 1)) * INF + f4;
            union { u16 h[4]; u64 q8; } pk2;
#pragma unroll
            for (int i = 0; i < 4; ++i) pk2.h[i] = f2bf(src[i]);
            ast64(&p.XD0[(size_t)pn * SXD0 + (size_t)b * KD0 + 1056 + f4], pk2.q8);
        }
    }
}

// out = a @ W2^T (32 x 128), blocks 0-15, waves 0-3 split K, LDS-reduce.
__device__ __forceinline__ void dec_D_body(const KParams& p, int t, float* sred) {
    const int wg = blockIdx.x;
    const int pn = (t & 1) ^ 1;
    const int tid = threadIdx.x, lane = tid & 63, w = tid >> 6;
    const int l15 = lane & 15, kq = lane >> 4;
    const int mt = wg & 1, nt = wg >> 1;
    if (w < 4) {
        const u16* Wr = p.WH2 + (size_t)(mt * 16 + l15) * KH + kq * 8;
        const u16* Xb = p.Abuf + (size_t)(nt * 16 + l15) * KH + kq * 8;
        f32x4 acc = {0.f, 0.f, 0.f, 0.f};
#pragma unroll 8
        for (int kb = w * 8; kb < w * 8 + 8; ++kb) {
            const int o = kb * 32;
            acc = mfma16(*(const bf16x8*)(Wr + o), ldx(Xb + o), acc);
        }
#pragma unroll
        for (int q = 0; q < 4; ++q) sred[(w * 64 + lane) * 4 + q] = acc[q];
    }
    __syncthreads();
    if (w == 0) {
        int b = nt * 16 + l15;
        union { u16 h[4]; u64 q8; } pk;
#pragma unroll
        for (int q = 0; q < 4; ++q) {
            float s = sred[(0 * 64 + lane) * 4 + q] + sred[(1 * 64 + lane) * 4 + q] +
                      sred[(2 * 64 + lane) * 4 + q] + sred[(3 * 64 + lane) * 4 + q];
            int feat = mt * 16 + kq * 4 + q;
            p.out[(size_t)b * (TOUT * OUTF) + t * OUTF + feat] = s;
            pk.h[q] = f2bf(s);
        }
        ast64(&p.XD0[(size_t)pn * SXD0 + (size_t)b * KD0 + 1024 + mt * 16 + kq * 4], pk.q8);
    }
}

// ---------------- the persistent kernel ----------------
__global__ void __launch_bounds__(512, 1) seq2seq_persist(KParams p) {
    __shared__ float sred[4 * 64 * 17];
    unsigned target = 0;

    // encoder: 513 pipelined rounds
    for (int r = 0; r < 513; ++r) {
        enc_round_body(p, r, sred);
        gridbar(p.bar, ++target);
    }

    // transition
    transition_body(p);
    gridbar(p.bar, ++target);

    // decoder: 64 steps x 4 rounds
    for (int t = 0; t < TOUT; ++t) {
        if (blockIdx.x < 128) dec_A_body(p, t, sred);
        gridbar(p.bar, ++target);
        if (blockIdx.x < 128) dec_B_body(p, t, sred);
        gridbar(p.bar, ++target);
        if (blockIdx.x < 128) dec_C_body(p, t);
        gridbar(p.bar, ++target);
        if (blockIdx.x < 16) dec_D_body(p, t, sred);
        if (t + 1 < TOUT) gridbar(p.bar, ++target);
    }
}

// ---------------- host launch ----------------
extern "C" void kernel_launch(void* const* d_in, const int* in_sizes, int n_in,
                              void* d_out, int out_size, void* d_ws, size_t ws_size,
                              hipStream_t stream) {
    const float* enc_input = (const float*)d_in[0];
    const float* dec_input = (const float*)d_in[1];
    const float* enc_Wih0 = (const float*)d_in[2];
    const float* enc_Whh0 = (const float*)d_in[3];
    const float* enc_bih0 = (const float*)d_in[4];
    const float* enc_bhh0 = (const float*)d_in[5];
    const float* enc_Wih1 = (const float*)d_in[6];
    const float* enc_Whh1 = (const float*)d_in[7];
    const float* enc_bih1 = (const float*)d_in[8];
    const float* enc_bhh1 = (const float*)d_in[9];
    const float* dec_Wih0 = (const float*)d_in[10];
    const float* dec_Whh0 = (const float*)d_in[11];
    const float* dec_bih0 = (const float*)d_in[12];
    const float* dec_bhh0 = (const float*)d_in[13];
    const float* dec_Wih1 = (const float*)d_in[14];
    const float* dec_Whh1 = (const float*)d_in[15];
    const float* dec_bih1 = (const float*)d_in[16];
    const float* dec_bhh1 = (const float*)d_in[17];
    const float* out1_W = (const float*)d_in[18];
    const float* out1_b = (const float*)d_in[19];
    const float* out2_W = (const float*)d_in[20];

    char* ws = (char*)d_ws;
    size_t off = 0;
    auto alloc = [&](size_t bytes) { size_t o = off; off = (off + bytes + 255) & ~(size_t)255; return o; };

    u16* W0 = (u16*)(ws + alloc((size_t)H3 * K0 * 2));
    u16* W1 = (u16*)(ws + alloc((size_t)H3 * K1 * 2));
    u16* WD0 = (u16*)(ws + alloc((size_t)H3 * KD0 * 2));
    u16* WD1 = (u16*)(ws + alloc((size_t)H3 * KD1 * 2));
    u16* WH1 = (u16*)(ws + alloc((size_t)Hdim * KH * 2));
    u16* WH2 = (u16*)(ws + alloc((size_t)OUTF * KH * 2));
    float* B0 = (float*)(ws + alloc(4096 * 4));
    float* B1 = (float*)(ws + alloc(4096 * 4));
    float* BD0 = (float*)(ws + alloc(4096 * 4));
    float* BD1 = (float*)(ws + alloc(4096 * 4));
    float* HB = (float*)(ws + alloc(1024 * 4));
    u16* X0 = (u16*)(ws + alloc((size_t)2 * Bsz * K0 * 2));
    u16* X1 = (u16*)(ws + alloc((size_t)2 * Bsz * K1 * 2));
    u16* XD0 = (u16*)(ws + alloc((size_t)2 * Bsz * KD0 * 2));
    u16* XD1 = (u16*)(ws + alloc((size_t)2 * Bsz * KD1 * 2));
    float* H0f = (float*)(ws + alloc((size_t)2 * Bsz * Hdim * 4));
    float* H1f = (float*)(ws + alloc((size_t)2 * Bsz * Hdim * 4));
    u16* Hhead = (u16*)(ws + alloc((size_t)Bsz * KH * 2));
    u16* Abuf = (u16*)(ws + alloc((size_t)Bsz * KH * 2));
    unsigned* bar = (unsigned*)(ws + alloc(BAR_WORDS * 4));

    // --- prologue: weight/bias repack (h-part FIRST) + state/barrier init ---
    pack2<<<dim3((K0 + 255) / 256, H3), 256, 0, stream>>>(enc_Whh0, 1024, enc_Wih0, 64, W0);
    pack2<<<dim3((K1 + 255) / 256, H3), 256, 0, stream>>>(enc_Whh1, 1024, enc_Wih1, 1024, W1);
    pack2<<<dim3((KD0 + 255) / 256, H3), 256, 0, stream>>>(dec_Whh0, 1024, dec_Wih0, 96, WD0);
    pack2<<<dim3((KD1 + 255) / 256, H3), 256, 0, stream>>>(dec_Whh1, 1024, dec_Wih1, 1024, WD1);
    pack2<<<dim3((KH + 255) / 256, Hdim), 256, 0, stream>>>(out1_W, 1024, nullptr, 0, WH1);
    pack2<<<dim3((KH + 255) / 256, OUTF), 256, 0, stream>>>(out2_W, 1024, nullptr, 0, WH2);
    pack_bias<<<4, 256, 0, stream>>>(enc_bih0, enc_bhh0, enc_bih1, enc_bhh1,
                                     dec_bih0, dec_bhh0, dec_bih1, dec_bhh1,
                                     out1_b, B0, B1, BD0, BD1, HB);
    init_state<<<256, 256, 0, stream>>>(enc_input, X0, X1, H0f, H1f, bar);

    KParams kp;
    kp.enc_input = enc_input; kp.dec_input = dec_input;
    kp.W0 = W0; kp.W1 = W1; kp.WD0 = WD0; kp.WD1 = WD1; kp.WH1 = WH1; kp.WH2 = WH2;
    kp.B0 = B0; kp.B1 = B1; kp.BD0 = BD0; kp.BD1 = BD1; kp.HB = HB;
    kp.X0 = X0; kp.X1 = X1; kp.XD0 = XD0; kp.XD1 = XD1; kp.Hhead = Hhead; kp.Abuf = Abuf;
    kp.H0f = H0f; kp.H1f = H1f;
    kp.out = (float*)d_out;
    kp.bar = bar;

    // --- one persistent kernel: software grid barrier between rounds ---
    seq2seq_persist<<<256, 512, 0, stream>>>(kp);
}

// Round 7
// 23486.128 us; speedup vs baseline: 2.5871x; 1.2577x over previous
//
#include <hip/hip_runtime.h>

typedef unsigned short u16;
typedef unsigned long long u64;
typedef __attribute__((ext_vector_type(8))) short bf16x8;
typedef __attribute__((ext_vector_type(4))) float f32x4;

// ---------------- constants ----------------
#define Bsz   128
#define TIN   512
#define TOUT  64
#define INF   64
#define OUTF  32
#define Hdim  1024
#define H3    3072

// K layouts: H-PART FIRST everywhere (uniform n-gate split at kb=32)
#define K0    1088   // enc L0: [h(1024) | x(64)]
#define K1    2048   // enc L1: [h1(1024) | y0(1024)]
#define KD0   1120   // dec L0: [h(1024) | yp(32) x(64)]
#define KD1   2048   // dec L1: [h1(1024) | h0(1024)]
#define KH    1024

#define SX0  (Bsz * K0)
#define SX1  (Bsz * K1)
#define SXD0 (Bsz * KD0)
#define SXD1 (Bsz * KD1)
#define SH   (Bsz * Hdim)

// barrier layout in u32 words: leaves at i*16 (i<32), root at 512, gen at 528
#define BAR_ROOT 512
#define BAR_GEN  528
#define BAR_WORDS 544

__device__ __forceinline__ u16 f2bf(float f) {
    union { float f; unsigned u; } c; c.f = f;
    unsigned u = c.u;
    unsigned r = (u + 0x7fffu + ((u >> 16) & 1u)) >> 16;
    return (u16)r;
}

__device__ __forceinline__ f32x4 mfma16(bf16x8 a, bf16x8 b, f32x4 c) {
    return __builtin_amdgcn_mfma_f32_16x16x32_bf16(a, b, c, 0, 0, 0);
}

// XCD-aware tile map for 32h x 32b tiles: 128 blocks -> 32 h-tiles x 4
// batch-quarters; blocks with equal (wg % 8) share an XCD and own a disjoint
// 1/8 of weight rows (4 h-tiles) -> per-XCD weight set ~2.4 MB < 4 MiB L2.
__device__ __forceinline__ void tile_map32(int wg, int& htile, int& bq) {
    const int xcd = wg & 7, idx = wg >> 3;
    htile = ((idx & 3) << 3) + xcd;   // 0..31
    bq = idx >> 2;                    // 0..3
}

// ---------- agent-coherent (IF$-level) state accessors ----------
__device__ __forceinline__ u64 ald64(const void* p) {
    return __hip_atomic_load((const u64*)p, __ATOMIC_RELAXED, __HIP_MEMORY_SCOPE_AGENT);
}
__device__ __forceinline__ void ast64(void* p, u64 v) {
    __hip_atomic_store((u64*)p, v, __ATOMIC_RELAXED, __HIP_MEMORY_SCOPE_AGENT);
}
__device__ __forceinline__ float aldf(const float* p) {
    return __hip_atomic_load(p, __ATOMIC_RELAXED, __HIP_MEMORY_SCOPE_AGENT);
}
__device__ __forceinline__ void astf(float* p, float v) {
    __hip_atomic_store(p, v, __ATOMIC_RELAXED, __HIP_MEMORY_SCOPE_AGENT);
}
__device__ __forceinline__ u16 aldu16(const u16* p) {
    return __hip_atomic_load(p, __ATOMIC_RELAXED, __HIP_MEMORY_SCOPE_AGENT);
}
__device__ __forceinline__ void astu16(u16* p, u16 v) {
    __hip_atomic_store(p, v, __ATOMIC_RELAXED, __HIP_MEMORY_SCOPE_AGENT);
}
__device__ __forceinline__ bf16x8 ldx(const u16* p) {
    union { u64 q[2]; bf16x8 v; } u;
    u.q[0] = ald64(p);
    u.q[1] = ald64(p + 4);
    return u.v;
}

// ---------------- software grid barrier (multi-XCD safe, no cache ops) ----
__device__ __forceinline__ void gridbar(unsigned* bar, unsigned target) {
    __syncthreads();
    if (threadIdx.x == 0) {
        asm volatile("s_waitcnt vmcnt(0) lgkmcnt(0)" ::: "memory");
        unsigned leaf = (blockIdx.x >> 3) << 4;
        unsigned a = __hip_atomic_fetch_add(&bar[leaf], 1u,
                        __ATOMIC_RELAXED, __HIP_MEMORY_SCOPE_AGENT);
        if (((a + 1u) & 7u) == 0u) {
            unsigned r = __hip_atomic_fetch_add(&bar[BAR_ROOT], 1u,
                            __ATOMIC_RELAXED, __HIP_MEMORY_SCOPE_AGENT);
            if (((r + 1u) & 31u) == 0u)
                __hip_atomic_fetch_add(&bar[BAR_GEN], 1u,
                        __ATOMIC_RELAXED, __HIP_MEMORY_SCOPE_AGENT);
        }
        while (__hip_atomic_load(&bar[BAR_GEN],
                    __ATOMIC_RELAXED, __HIP_MEMORY_SCOPE_AGENT) < target)
            __builtin_amdgcn_s_sleep(2);
        asm volatile("" ::: "memory");
    }
    __syncthreads();
}

// ---------------- LDS X staging ----------------
// Copy 32 rows x K bf16 from agent-coherent state into LDS, fully parallel
// (512 threads, 8 loads in flight each). XOR-swizzle byte^((row&7)<<4) on the
// write; reads use the same mapping (bijective both sides).
template <int K>
__device__ __forceinline__ void stage_x(const u16* __restrict__ Xsrc, u16* __restrict__ xl) {
    const int tid = threadIdx.x;
    const int r = tid >> 4, tj = tid & 15;
    const u16* srow = Xsrc + (size_t)r * K;
    const unsigned base = (unsigned)(r * K * 2);
    const unsigned swz = (unsigned)((r & 7) << 4);
    constexpr int U = K / 4;   // 8-byte units per row
    for (int k0 = tj; k0 < U; k0 += 128) {
        u64 tmp[8];
#pragma unroll
        for (int i = 0; i < 8; ++i) {
            int k4 = k0 + i * 16;
            if (k4 < U) tmp[i] = ald64(srow + k4 * 4);
        }
#pragma unroll
        for (int i = 0; i < 8; ++i) {
            int k4 = k0 + i * 16;
            if (k4 < U) *(u64*)((char*)xl + ((base + (unsigned)k4 * 8u) ^ swz)) = tmp[i];
        }
    }
}

// ---------------- K-split GRU wave (W: plain L2 loads; X: LDS) ----------
template <int KB0, int KB1, int SPLIT, int K>
__device__ __forceinline__ void gru_wave_lds(
        const u16* __restrict__ W, const u16* __restrict__ xl,
        int j0w, int row,
        f32x4& accR, f32x4& accZ, f32x4& accN0, f32x4& accN1) {
    const int lane = threadIdx.x & 63;
    const int l15 = lane & 15, kq = lane >> 4;
    const u16* Wr = W + (size_t)(j0w + l15) * K + kq * 8;
    const u16* Wz = Wr + (size_t)1024 * K;
    const u16* Wn = Wz + (size_t)1024 * K;
    const unsigned xbase = (unsigned)(row * K * 2 + kq * 16);
    const unsigned swz = (unsigned)((row & 7) << 4);
    accR = (f32x4){0.f, 0.f, 0.f, 0.f};
    accZ = (f32x4){0.f, 0.f, 0.f, 0.f};
    accN0 = (f32x4){0.f, 0.f, 0.f, 0.f};
    accN1 = (f32x4){0.f, 0.f, 0.f, 0.f};
    constexpr int E0 = (SPLIT < KB1) ? SPLIT : KB1;
    constexpr int S1 = (SPLIT > KB0) ? SPLIT : KB0;
#pragma unroll 8
    for (int kb = KB0; kb < E0; ++kb) {
        const int o = kb * 32;
        bf16x8 xb = *(const bf16x8*)((const char*)xl + ((xbase + (unsigned)kb * 64u) ^ swz));
        accR  = mfma16(*(const bf16x8*)(Wr + o), xb, accR);
        accZ  = mfma16(*(const bf16x8*)(Wz + o), xb, accZ);
        accN0 = mfma16(*(const bf16x8*)(Wn + o), xb, accN0);
    }
#pragma unroll 8
    for (int kb = S1; kb < KB1; ++kb) {
        const int o = kb * 32;
        bf16x8 xb = *(const bf16x8*)((const char*)xl + ((xbase + (unsigned)kb * 64u) ^ swz));
        accR  = mfma16(*(const bf16x8*)(Wr + o), xb, accR);
        accZ  = mfma16(*(const bf16x8*)(Wz + o), xb, accZ);
        accN1 = mfma16(*(const bf16x8*)(Wn + o), xb, accN1);
    }
}

// ---------------- WG-level GRU tile: 32 h-rows x 32 batch ----------------
// 8 waves: (hf, bf) in 2x2 fragments x 2 K-halves (grp). LDS combine of the
// two K-half partials, then gate math + state writes (agent-coherent).
template <int KBT, int SPLIT, int K>
__device__ __forceinline__ void gru_block32(
        const u16* __restrict__ W, const u16* __restrict__ X,
        const float* __restrict__ Hold, const float* __restrict__ Bias,
        int htile, int bq,
        float* __restrict__ Hnew,
        u16* __restrict__ O1, int ld1, int off1,
        u16* __restrict__ O2, int ld2, int off2,
        float* __restrict__ sred /* [4][64][17] */, u16* __restrict__ xl) {
    stage_x<K>(X + (size_t)bq * 32 * K, xl);
    __syncthreads();

    const int tid = threadIdx.x, lane = tid & 63, w = tid >> 6;
    const int hf = w & 1, bf = (w >> 1) & 1, grp = w >> 2, bg = w & 3;
    const int l15 = lane & 15, kq = lane >> 4;
    const int j0w = htile * 32 + hf * 16;
    const int rowl = bf * 16 + l15;
    constexpr int MID = KBT / 2;

    f32x4 aR, aZ, aN0, aN1;
    if (grp == 0) gru_wave_lds<0, MID, SPLIT, K>(W, xl, j0w, rowl, aR, aZ, aN0, aN1);
    else          gru_wave_lds<MID, KBT, SPLIT, K>(W, xl, j0w, rowl, aR, aZ, aN0, aN1);

    float* slot = sred + ((size_t)bg * 64 + lane) * 17;
    if (grp == 1) {
#pragma unroll
        for (int q = 0; q < 4; ++q) {
            slot[q]      = aR[q];
            slot[4 + q]  = aZ[q];
            slot[8 + q]  = aN0[q];
            slot[12 + q] = aN1[q];
        }
    }
    __syncthreads();
    if (grp == 0) {
        const int nb = bq * 32 + bf * 16 + l15;
        float hv4[4];
#pragma unroll
        for (int q = 0; q < 4; ++q) {
            const int j = j0w + kq * 4 + q;
            float R  = aR[q]  + slot[q];
            float Z  = aZ[q]  + slot[4 + q];
            float Nh = aN0[q] + slot[8 + q];
            float Ni = aN1[q] + slot[12 + q];
            float r = 1.f / (1.f + expf(-(R + Bias[j])));
            float z = 1.f / (1.f + expf(-(Z + Bias[1024 + j])));
            float n = tanhf(Ni + Bias[2048 + j] + r * (Nh + Bias[3072 + j]));
            float ho = aldf(&Hold[(size_t)j * Bsz + nb]);
            float hv = (1.f - z) * n + z * ho;
            astf(&Hnew[(size_t)j * Bsz + nb], hv);
            hv4[q] = hv;
        }
        union { u16 h[4]; u64 q8; } pk;
#pragma unroll
        for (int q = 0; q < 4; ++q) pk.h[q] = f2bf(hv4[q]);
        ast64(&O1[(size_t)nb * ld1 + off1 + j0w + kq * 4], pk.q8);
        if (O2) ast64(&O2[(size_t)nb * ld2 + off2 + j0w + kq * 4], pk.q8);
    }
}

// ---------------- prologue kernels ----------------

__global__ void __launch_bounds__(256) pack2(
        const float* __restrict__ A, int KA,
        const float* __restrict__ Bs, int KB,
        u16* __restrict__ dst) {
    int row = blockIdx.y;
    int k = blockIdx.x * 256 + threadIdx.x;
    int K = KA + KB;
    if (k >= K) return;
    float v = (k < KA) ? A[(size_t)row * KA + k] : Bs[(size_t)row * KB + (k - KA)];
    dst[(size_t)row * K + k] = f2bf(v);
}

__global__ void __launch_bounds__(256) pack_bias(
        const float* bi0e, const float* bh0e,
        const float* bi1e, const float* bh1e,
        const float* bi0d, const float* bh0d,
        const float* bi1d, const float* bh1d,
        const float* out1b,
        float* B0, float* B1, float* BD0, float* BD1, float* HB) {
    int j = blockIdx.x * blockDim.x + threadIdx.x;
    if (j >= 1024) return;
    const float* bis[4] = { bi0e, bi1e, bi0d, bi1d };
    const float* bhs[4] = { bh0e, bh1e, bh0d, bh1d };
    float* ds[4] = { B0, B1, BD0, BD1 };
#pragma unroll
    for (int s = 0; s < 4; ++s) {
        ds[s][j]        = bis[s][j]        + bhs[s][j];
        ds[s][1024 + j] = bis[s][1024 + j] + bhs[s][1024 + j];
        ds[s][2048 + j] = bis[s][2048 + j];
        ds[s][3072 + j] = bhs[s][2048 + j];
    }
    HB[j] = out1b[j];
}

__global__ void __launch_bounds__(256) init_state(
        const float* __restrict__ enc_input,
        u16* __restrict__ X0, u16* __restrict__ X1,
        float* __restrict__ H0f, float* __restrict__ H1f,
        unsigned* __restrict__ bar) {
    int gtid = blockIdx.x * blockDim.x + threadIdx.x;
    int G = gridDim.x * blockDim.x;
    for (int i = gtid; i < BAR_WORDS; i += G) bar[i] = 0u;
    for (int i = gtid; i < Bsz * Hdim; i += G) { int b = i >> 10, j = i & 1023; X0[(size_t)b * K0 + j] = 0; }
    for (int i = gtid; i < Bsz * INF; i += G) { int b = i >> 6, f = i & 63;
        X0[(size_t)b * K0 + 1024 + f] = f2bf(enc_input[(size_t)b * (TIN * INF) + f]); }
    for (int i = gtid; i < Bsz * Hdim; i += G) { int b = i >> 10, j = i & 1023;
        X1[(size_t)SX1 + (size_t)b * K1 + j] = 0; }
    for (int i = gtid; i < Bsz * Hdim; i += G) { H0f[i] = 0.f; H1f[SH + i] = 0.f; }
}

// ---------------- params ----------------
struct KParams {
    const float* enc_input;
    const float* dec_input;
    const u16 *W0, *W1, *WD0, *WD1, *WH1, *WH2;
    const float *B0, *B1, *BD0, *BD1, *HB;
    u16 *X0, *X1, *XD0, *XD1, *Hhead, *Abuf;
    float *H0f, *H1f;
    float* out;
    unsigned* bar;
};

// ---------------- round bodies ----------------

__device__ __forceinline__ void enc_round_body(const KParams& p, int r,
                                               float* sred, u16* xl) {
    const int wg = blockIdx.x;
    const int pr = r & 1, pw = pr ^ 1;
    if (wg < 128) {
        if (r < 512) {
            int htile, bq; tile_map32(wg, htile, bq);
            gru_block32<34, 32, K0>(p.W0, p.X0 + pr * SX0, p.H0f + pr * SH, p.B0,
                                    htile, bq,
                                    p.H0f + pw * SH,
                                    p.X0 + pw * SX0, K0, 0,
                                    p.X1 + pw * SX1, K1, 1024, sred, xl);
            if (r + 1 < 512 && threadIdx.x < 16) {
                int b = wg, f4 = threadIdx.x * 4;
                const float* src = p.enc_input + ((size_t)b * TIN + (r + 1)) * INF + f4;
                union { u16 h[4]; u64 q8; } pk;
#pragma unroll
                for (int i = 0; i < 4; ++i) pk.h[i] = f2bf(src[i]);
                ast64(&p.X0[(size_t)pw * SX0 + (size_t)b * K0 + 1024 + f4], pk.q8);
            }
        }
    } else {
        if (r >= 1) {
            int htile, bq; tile_map32(wg - 128, htile, bq);
            gru_block32<64, 32, K1>(p.W1, p.X1 + pr * SX1, p.H1f + pr * SH, p.B1,
                                    htile, bq,
                                    p.H1f + pw * SH,
                                    p.X1 + pw * SX1, K1, 0,
                                    (u16*)nullptr, 0, 0, sred, xl);
        }
    }
}

__device__ __forceinline__ void transition_body(const KParams& p) {
    int gtid = blockIdx.x * blockDim.x + threadIdx.x;
    const int G = 256 * 512;
    for (int i = gtid; i < SH; i += G)
        astf(&p.H1f[i], aldf(&p.H1f[SH + i]));
    for (int i = gtid; i < Bsz * Hdim; i += G) {
        int b = i >> 10, j = i & 1023;
        astu16(&p.XD0[(size_t)b * KD0 + j], aldu16(&p.X0[(size_t)b * K0 + j]));
    }
    for (int i = gtid; i < Bsz * OUTF; i += G) {
        int b = i >> 5, f = i & 31;
        astu16(&p.XD0[(size_t)b * KD0 + 1024 + f],
               f2bf(p.enc_input[((size_t)b * TIN + (TIN - 1)) * INF + f]));
    }
    for (int i = gtid; i < Bsz * INF; i += G) {
        int b = i >> 6, f = i & 63;
        astu16(&p.XD0[(size_t)b * KD0 + 1056 + f],
               f2bf(p.dec_input[(size_t)b * (TOUT * INF) + f]));
    }
    for (int i = gtid; i < Bsz * Hdim; i += G) {
        int b = i >> 10, j = i & 1023;
        astu16(&p.XD1[(size_t)b * KD1 + j],
               aldu16(&p.X1[(size_t)SX1 + (size_t)b * K1 + j]));
    }
}

__device__ __forceinline__ void dec_A_body(const KParams& p, int t, float* sred, u16* xl) {
    const int wg = blockIdx.x;
    const int pt = t & 1, pn = pt ^ 1;
    int htile, bq; tile_map32(wg, htile, bq);
    gru_block32<35, 32, KD0>(p.WD0, p.XD0 + pt * SXD0, p.H0f + pt * SH, p.BD0,
                             htile, bq,
                             p.H0f + pn * SH,
                             p.XD0 + pn * SXD0, KD0, 0,
                             p.XD1 + pt * SXD1, KD1, 1024, sred, xl);
}

__device__ __forceinline__ void dec_B_body(const KParams& p, int t, float* sred, u16* xl) {
    const int wg = blockIdx.x;
    const int pt = t & 1, pn = pt ^ 1;
    int htile, bq; tile_map32(wg, htile, bq);
    gru_block32<64, 32, KD1>(p.WD1, p.XD1 + pt * SXD1, p.H1f + pt * SH, p.BD1,
                             htile, bq,
                             p.H1f + pn * SH,
                             p.XD1 + pn * SXD1, KD1, 0,
                             p.Hhead, KH, 0, sred, xl);
}

// a = relu(h1 @ W1^T + b): 32 out-rows x 32 batch per block, LDS-staged Hhead.
__device__ __forceinline__ void dec_C_body(const KParams& p, int t, float* sred, u16* xl) {
    const int wg = blockIdx.x;
    const int pn = (t & 1) ^ 1;
    int htile, bq; tile_map32(wg, htile, bq);
    stage_x<KH>(p.Hhead + (size_t)bq * 32 * KH, xl);
    __syncthreads();

    const int tid = threadIdx.x, lane = tid & 63, w = tid >> 6;
    const int hf = w & 1, bf = (w >> 1) & 1, grp = w >> 2, bg = w & 3;
    const int l15 = lane & 15, kq = lane >> 4;
    const int j0w = htile * 32 + hf * 16;
    const int rowl = bf * 16 + l15;

    const u16* Wr = p.WH1 + (size_t)(j0w + l15) * KH + kq * 8;
    const unsigned xbase = (unsigned)(rowl * KH * 2 + kq * 16);
    const unsigned swz = (unsigned)((rowl & 7) << 4);
    f32x4 acc = {0.f, 0.f, 0.f, 0.f};
    const int kb0 = grp * 16, kb1 = kb0 + 16;
#pragma unroll 8
    for (int kb = kb0; kb < kb1; ++kb) {
        bf16x8 xb = *(const bf16x8*)((const char*)xl + ((xbase + (unsigned)kb * 64u) ^ swz));
        acc = mfma16(*(const bf16x8*)(Wr + kb * 32), xb, acc);
    }
    float* slot = sred + ((size_t)bg * 64 + lane) * 17;
    if (grp == 1) {
#pragma unroll
        for (int q = 0; q < 4; ++q) slot[q] = acc[q];
    }
    __syncthreads();
    if (grp == 0) {
        const int nb = bq * 32 + bf * 16 + l15;
        union { u16 h[4]; u64 q8; } pk;
#pragma unroll
        for (int q = 0; q < 4; ++q) {
            const int j = j0w + kq * 4 + q;
            float v = acc[q] + slot[q] + p.HB[j];
            pk.h[q] = f2bf(v > 0.f ? v : 0.f);
        }
        ast64(&p.Abuf[(size_t)nb * KH + j0w + kq * 4], pk.q8);
    }
    if (t + 1 < TOUT && tid < 16) {
        int b = wg, f4 = tid * 4;
        const float* src = p.dec_input + ((size_t)b * TOUT + (t + 1)) * INF + f4;
        union { u16 h[4]; u64 q8; } pk2;
#pragma unroll
        for (int i = 0; i < 4; ++i) pk2.h[i] = f2bf(src[i]);
        ast64(&p.XD0[(size_t)pn * SXD0 + (size_t)b * KD0 + 1056 + f4], pk2.q8);
    }
}

// out = a @ W2^T (32 x 128), blocks 0-15, waves 0-3 split K, LDS-reduce.
__device__ __forceinline__ void dec_D_body(const KParams& p, int t, float* sred) {
    const int wg = blockIdx.x;
    const int pn = (t & 1) ^ 1;
    const int tid = threadIdx.x, lane = tid & 63, w = tid >> 6;
    const int l15 = lane & 15, kq = lane >> 4;
    const int mt = wg & 1, nt = wg >> 1;
    if (w < 4) {
        const u16* Wr = p.WH2 + (size_t)(mt * 16 + l15) * KH + kq * 8;
        const u16* Xb = p.Abuf + (size_t)(nt * 16 + l15) * KH + kq * 8;
        f32x4 acc = {0.f, 0.f, 0.f, 0.f};
#pragma unroll 8
        for (int kb = w * 8; kb < w * 8 + 8; ++kb) {
            const int o = kb * 32;
            acc = mfma16(*(const bf16x8*)(Wr + o), ldx(Xb + o), acc);
        }
#pragma unroll
        for (int q = 0; q < 4; ++q) sred[(w * 64 + lane) * 4 + q] = acc[q];
    }
    __syncthreads();
    if (w == 0) {
        int b = nt * 16 + l15;
        union { u16 h[4]; u64 q8; } pk;
#pragma unroll
        for (int q = 0; q < 4; ++q) {
            float s = sred[(0 * 64 + lane) * 4 + q] + sred[(1 * 64 + lane) * 4 + q] +
                      sred[(2 * 64 + lane) * 4 + q] + sred[(3 * 64 + lane) * 4 + q];
            int feat = mt * 16 + kq * 4 + q;
            p.out[(size_t)b * (TOUT * OUTF) + t * OUTF + feat] = s;
            pk.h[q] = f2bf(s);
        }
        ast64(&p.XD0[(size_t)pn * SXD0 + (size_t)b * KD0 + 1024 + mt * 16 + kq * 4], pk.q8);
    }
}

// ---------------- the persistent kernel ----------------
__global__ void __launch_bounds__(512, 1) seq2seq_persist(KParams p) {
    __shared__ float sred[4 * 64 * 17];          // 17.4 KB
    __shared__ u16 xls[32 * 2048];               // 128 KB staged X slab
    unsigned target = 0;

    // encoder: 513 pipelined rounds
    for (int r = 0; r < 513; ++r) {
        enc_round_body(p, r, sred, xls);
        gridbar(p.bar, ++target);
    }

    // transition
    transition_body(p);
    gridbar(p.bar, ++target);

    // decoder: 64 steps x 4 rounds
    for (int t = 0; t < TOUT; ++t) {
        if (blockIdx.x < 128) dec_A_body(p, t, sred, xls);
        gridbar(p.bar, ++target);
        if (blockIdx.x < 128) dec_B_body(p, t, sred, xls);
        gridbar(p.bar, ++target);
        if (blockIdx.x < 128) dec_C_body(p, t, sred, xls);
        gridbar(p.bar, ++target);
        if (blockIdx.x < 16) dec_D_body(p, t, sred);
        if (t + 1 < TOUT) gridbar(p.bar, ++target);
    }
}

// ---------------- host launch ----------------
extern "C" void kernel_launch(void* const* d_in, const int* in_sizes, int n_in,
                              void* d_out, int out_size, void* d_ws, size_t ws_size,
                              hipStream_t stream) {
    const float* enc_input = (const float*)d_in[0];
    const float* dec_input = (const float*)d_in[1];
    const float* enc_Wih0 = (const float*)d_in[2];
    const float* enc_Whh0 = (const float*)d_in[3];
    const float* enc_bih0 = (const float*)d_in[4];
    const float* enc_bhh0 = (const float*)d_in[5];
    const float* enc_Wih1 = (const float*)d_in[6];
    const float* enc_Whh1 = (const float*)d_in[7];
    const float* enc_bih1 = (const float*)d_in[8];
    const float* enc_bhh1 = (const float*)d_in[9];
    const float* dec_Wih0 = (const float*)d_in[10];
    const float* dec_Whh0 = (const float*)d_in[11];
    const float* dec_bih0 = (const float*)d_in[12];
    const float* dec_bhh0 = (const float*)d_in[13];
    const float* dec_Wih1 = (const float*)d_in[14];
    const float* dec_Whh1 = (const float*)d_in[15];
    const float* dec_bih1 = (const float*)d_in[16];
    const float* dec_bhh1 = (const float*)d_in[17];
    const float* out1_W = (const float*)d_in[18];
    const float* out1_b = (const float*)d_in[19];
    const float* out2_W = (const float*)d_in[20];

    char* ws = (char*)d_ws;
    size_t off = 0;
    auto alloc = [&](size_t bytes) { size_t o = off; off = (off + bytes + 255) & ~(size_t)255; return o; };

    u16* W0 = (u16*)(ws + alloc((size_t)H3 * K0 * 2));
    u16* W1 = (u16*)(ws + alloc((size_t)H3 * K1 * 2));
    u16* WD0 = (u16*)(ws + alloc((size_t)H3 * KD0 * 2));
    u16* WD1 = (u16*)(ws + alloc((size_t)H3 * KD1 * 2));
    u16* WH1 = (u16*)(ws + alloc((size_t)Hdim * KH * 2));
    u16* WH2 = (u16*)(ws + alloc((size_t)OUTF * KH * 2));
    float* B0 = (float*)(ws + alloc(4096 * 4));
    float* B1 = (float*)(ws + alloc(4096 * 4));
    float* BD0 = (float*)(ws + alloc(4096 * 4));
    float* BD1 = (float*)(ws + alloc(4096 * 4));
    float* HB = (float*)(ws + alloc(1024 * 4));
    u16* X0 = (u16*)(ws + alloc((size_t)2 * Bsz * K0 * 2));
    u16* X1 = (u16*)(ws + alloc((size_t)2 * Bsz * K1 * 2));
    u16* XD0 = (u16*)(ws + alloc((size_t)2 * Bsz * KD0 * 2));
    u16* XD1 = (u16*)(ws + alloc((size_t)2 * Bsz * KD1 * 2));
    float* H0f = (float*)(ws + alloc((size_t)2 * Bsz * Hdim * 4));
    float* H1f = (float*)(ws + alloc((size_t)2 * Bsz * Hdim * 4));
    u16* Hhead = (u16*)(ws + alloc((size_t)Bsz * KH * 2));
    u16* Abuf = (u16*)(ws + alloc((size_t)Bsz * KH * 2));
    unsigned* bar = (unsigned*)(ws + alloc(BAR_WORDS * 4));

    // --- prologue: weight/bias repack (h-part FIRST) + state/barrier init ---
    pack2<<<dim3((K0 + 255) / 256, H3), 256, 0, stream>>>(enc_Whh0, 1024, enc_Wih0, 64, W0);
    pack2<<<dim3((K1 + 255) / 256, H3), 256, 0, stream>>>(enc_Whh1, 1024, enc_Wih1, 1024, W1);
    pack2<<<dim3((KD0 + 255) / 256, H3), 256, 0, stream>>>(dec_Whh0, 1024, dec_Wih0, 96, WD0);
    pack2<<<dim3((KD1 + 255) / 256, H3), 256, 0, stream>>>(dec_Whh1, 1024, dec_Wih1, 1024, WD1);
    pack2<<<dim3((KH + 255) / 256, Hdim), 256, 0, stream>>>(out1_W, 1024, nullptr, 0, WH1);
    pack2<<<dim3((KH + 255) / 256, OUTF), 256, 0, stream>>>(out2_W, 1024, nullptr, 0, WH2);
    pack_bias<<<4, 256, 0, stream>>>(enc_bih0, enc_bhh0, enc_bih1, enc_bhh1,
                                     dec_bih0, dec_bhh0, dec_bih1, dec_bhh1,
                                     out1_b, B0, B1, BD0, BD1, HB);
    init_state<<<256, 256, 0, stream>>>(enc_input, X0, X1, H0f, H1f, bar);

    KParams kp;
    kp.enc_input = enc_input; kp.dec_input = dec_input;
    kp.W0 = W0; kp.W1 = W1; kp.WD0 = WD0; kp.WD1 = WD1; kp.WH1 = WH1; kp.WH2 = WH2;
    kp.B0 = B0; kp.B1 = B1; kp.BD0 = BD0; kp.BD1 = BD1; kp.HB = HB;
    kp.X0 = X0; kp.X1 = X1; kp.XD0 = XD0; kp.XD1 = XD1; kp.Hhead = Hhead; kp.Abuf = Abuf;
    kp.H0f = H0f; kp.H1f = H1f;
    kp.out = (float*)d_out;
    kp.bar = bar;

    // --- one persistent kernel: software grid barrier between rounds ---
    seq2seq_persist<<<256, 512, 0, stream>>>(kp);
}

// Round 8
// 21755.428 us; speedup vs baseline: 2.7929x; 1.0796x over previous
//
#include <hip/hip_runtime.h>

typedef unsigned short u16;
typedef unsigned long long u64;
typedef __attribute__((ext_vector_type(8))) short bf16x8;
typedef __attribute__((ext_vector_type(4))) float f32x4;

// ---------------- constants ----------------
#define Bsz   128
#define TIN   512
#define TOUT  64
#define INF   64
#define OUTF  32
#define Hdim  1024
#define H3    3072

// K layouts: H-PART FIRST everywhere (uniform n-gate split at kb=32)
#define K0    1088   // enc L0: [h(1024) | x(64)]
#define K1    2048   // enc L1: [h1(1024) | y0(1024)]
#define KD0   1120   // dec L0: [h(1024) | yp(32) x(64)]
#define KD1   2048   // dec L1: [h1(1024) | h0(1024)]
#define KH    1024

#define SX0  (Bsz * K0)
#define SX1  (Bsz * K1)
#define SXD0 (Bsz * KD0)
#define SXD1 (Bsz * KD1)
#define SH   (Bsz * Hdim)

// barrier words: global barrier uses 0..543 (leaves i*16, root 512, gen 528);
// group counters live at 1024 + g*32 (arrive) / +16 (gen), g < 24.
#define BAR_ROOT 512
#define BAR_GEN  528
#define GRP_BASE 1024
#define BAR_WORDS 2048

__device__ __forceinline__ u16 f2bf(float f) {
    union { float f; unsigned u; } c; c.f = f;
    unsigned u = c.u;
    unsigned r = (u + 0x7fffu + ((u >> 16) & 1u)) >> 16;
    return (u16)r;
}

__device__ __forceinline__ f32x4 mfma16(bf16x8 a, bf16x8 b, f32x4 c) {
    return __builtin_amdgcn_mfma_f32_16x16x32_bf16(a, b, c, 0, 0, 0);
}

// XCD-aware tile map: group bq = contiguous blocks [32bq,32bq+32) spanning all
// 8 XCDs; each XCD's 4 blocks own 4 disjoint htiles -> per-XCD weight slice
// ~2.4 MB < 4 MiB L2.
__device__ __forceinline__ void tile_map32(int wg, int& htile, int& bq) {
    const int xcd = wg & 7, idx = wg >> 3;
    htile = ((idx & 3) << 3) + xcd;   // 0..31
    bq = idx >> 2;                    // 0..3
}

// ---------- agent-coherent (IF$-level) state accessors ----------
__device__ __forceinline__ u64 ald64(const void* p) {
    return __hip_atomic_load((const u64*)p, __ATOMIC_RELAXED, __HIP_MEMORY_SCOPE_AGENT);
}
__device__ __forceinline__ void ast64(void* p, u64 v) {
    __hip_atomic_store((u64*)p, v, __ATOMIC_RELAXED, __HIP_MEMORY_SCOPE_AGENT);
}
__device__ __forceinline__ float aldf(const float* p) {
    return __hip_atomic_load(p, __ATOMIC_RELAXED, __HIP_MEMORY_SCOPE_AGENT);
}
__device__ __forceinline__ void astf(float* p, float v) {
    __hip_atomic_store(p, v, __ATOMIC_RELAXED, __HIP_MEMORY_SCOPE_AGENT);
}
__device__ __forceinline__ u16 aldu16(const u16* p) {
    return __hip_atomic_load(p, __ATOMIC_RELAXED, __HIP_MEMORY_SCOPE_AGENT);
}
__device__ __forceinline__ void astu16(u16* p, u16 v) {
    __hip_atomic_store(p, v, __ATOMIC_RELAXED, __HIP_MEMORY_SCOPE_AGENT);
}
__device__ __forceinline__ bf16x8 ldx(const u16* p) {
    union { u64 q[2]; bf16x8 v; } u;
    u.q[0] = ald64(p);
    u.q[1] = ald64(p + 4);
    return u.v;
}

// 16B coherent non-temporal load: sc0 sc1 = agent-coherent (bypass L1/L2 for
// correctness), nt = do NOT allocate in L2 -> weights stay L2-resident.
// Caller must s_waitcnt before consuming.
__device__ __forceinline__ void ldg16_nt(const u16* p, bf16x8& v) {
    asm volatile("global_load_dwordx4 %0, %1, off sc0 sc1 nt"
                 : "=&v"(v) : "v"(p));
}

// ---------------- sync primitives ----------------
// Group barrier among NB blocks (NB power of 2 arrivals pattern; D uses 4).
template <unsigned NB>
__device__ __forceinline__ void groupbar(unsigned* arr, unsigned* gen, unsigned target) {
    __syncthreads();
    if (threadIdx.x == 0) {
        asm volatile("s_waitcnt vmcnt(0) lgkmcnt(0)" ::: "memory");
        unsigned a = __hip_atomic_fetch_add(arr, 1u,
                        __ATOMIC_RELAXED, __HIP_MEMORY_SCOPE_AGENT);
        if (((a + 1u) & (NB - 1u)) == 0u)
            __hip_atomic_fetch_add(gen, 1u,
                        __ATOMIC_RELAXED, __HIP_MEMORY_SCOPE_AGENT);
        while (__hip_atomic_load(gen, __ATOMIC_RELAXED, __HIP_MEMORY_SCOPE_AGENT) < target)
            __builtin_amdgcn_s_sleep(2);
        asm volatile("" ::: "memory");
    }
    __syncthreads();
}

// Wait for an upstream group's gen (consumer side; no arrival).
__device__ __forceinline__ void waitgen(unsigned* gen, unsigned target) {
    if (threadIdx.x == 0) {
        while (__hip_atomic_load(gen, __ATOMIC_RELAXED, __HIP_MEMORY_SCOPE_AGENT) < target)
            __builtin_amdgcn_s_sleep(2);
        asm volatile("" ::: "memory");
    }
    __syncthreads();
}

// Global barrier (used only around the transition).
__device__ __forceinline__ void gridbar(unsigned* bar, unsigned target) {
    __syncthreads();
    if (threadIdx.x == 0) {
        asm volatile("s_waitcnt vmcnt(0) lgkmcnt(0)" ::: "memory");
        unsigned leaf = (blockIdx.x >> 3) << 4;
        unsigned a = __hip_atomic_fetch_add(&bar[leaf], 1u,
                        __ATOMIC_RELAXED, __HIP_MEMORY_SCOPE_AGENT);
        if (((a + 1u) & 7u) == 0u) {
            unsigned r = __hip_atomic_fetch_add(&bar[BAR_ROOT], 1u,
                            __ATOMIC_RELAXED, __HIP_MEMORY_SCOPE_AGENT);
            if (((r + 1u) & 31u) == 0u)
                __hip_atomic_fetch_add(&bar[BAR_GEN], 1u,
                        __ATOMIC_RELAXED, __HIP_MEMORY_SCOPE_AGENT);
        }
        while (__hip_atomic_load(&bar[BAR_GEN],
                    __ATOMIC_RELAXED, __HIP_MEMORY_SCOPE_AGENT) < target)
            __builtin_amdgcn_s_sleep(2);
        asm volatile("" ::: "memory");
    }
    __syncthreads();
}

__device__ __forceinline__ unsigned* grp_arr(unsigned* bar, int g) { return bar + GRP_BASE + g * 32; }
__device__ __forceinline__ unsigned* grp_gen(unsigned* bar, int g) { return bar + GRP_BASE + g * 32 + 16; }

// ---------------- prologue kernels ----------------

__global__ void __launch_bounds__(256) pack2(
        const float* __restrict__ A, int KA,
        const float* __restrict__ Bs, int KB,
        u16* __restrict__ dst) {
    int row = blockIdx.y;
    int k = blockIdx.x * 256 + threadIdx.x;
    int K = KA + KB;
    if (k >= K) return;
    float v = (k < KA) ? A[(size_t)row * KA + k] : Bs[(size_t)row * KB + (k - KA)];
    dst[(size_t)row * K + k] = f2bf(v);
}

__global__ void __launch_bounds__(256) pack_bias(
        const float* bi0e, const float* bh0e,
        const float* bi1e, const float* bh1e,
        const float* bi0d, const float* bh0d,
        const float* bi1d, const float* bh1d,
        const float* out1b,
        float* B0, float* B1, float* BD0, float* BD1, float* HB) {
    int j = blockIdx.x * blockDim.x + threadIdx.x;
    if (j >= 1024) return;
    const float* bis[4] = { bi0e, bi1e, bi0d, bi1d };
    const float* bhs[4] = { bh0e, bh1e, bh0d, bh1d };
    float* ds[4] = { B0, B1, BD0, BD1 };
#pragma unroll
    for (int s = 0; s < 4; ++s) {
        ds[s][j]        = bis[s][j]        + bhs[s][j];
        ds[s][1024 + j] = bis[s][1024 + j] + bhs[s][1024 + j];
        ds[s][2048 + j] = bis[s][2048 + j];
        ds[s][3072 + j] = bhs[s][2048 + j];
    }
    HB[j] = out1b[j];
}

__global__ void __launch_bounds__(256) init_state(
        const float* __restrict__ enc_input,
        u16* __restrict__ X0, u16* __restrict__ X1,
        float* __restrict__ H0f, float* __restrict__ H1f,
        unsigned* __restrict__ bar) {
    int gtid = blockIdx.x * blockDim.x + threadIdx.x;
    int G = gridDim.x * blockDim.x;
    for (int i = gtid; i < BAR_WORDS; i += G) bar[i] = 0u;
    for (int i = gtid; i < Bsz * Hdim; i += G) { int b = i >> 10, j = i & 1023; X0[(size_t)b * K0 + j] = 0; }
    for (int i = gtid; i < Bsz * INF; i += G) { int b = i >> 6, f = i & 63;
        X0[(size_t)b * K0 + 1024 + f] = f2bf(enc_input[(size_t)b * (TIN * INF) + f]); }
    // X1 parity1: h1-part (offset 0) = 0
    for (int i = gtid; i < Bsz * Hdim; i += G) { int b = i >> 10, j = i & 1023;
        X1[(size_t)SX1 + (size_t)b * K1 + j] = 0; }
    for (int i = gtid; i < Bsz * Hdim; i += G) { H0f[i] = 0.f; H1f[SH + i] = 0.f; }
}

// ---------------- LDS X staging (16B nt loads) ----------------
// Copy 32 rows x K bf16 from agent-coherent state into LDS. XOR-swizzle
// byte^((row&7)<<4) on write; reads use the same mapping.
template <int K>
__device__ __forceinline__ void stage_x(const u16* __restrict__ Xsrc, u16* __restrict__ xl) {
    const int tid = threadIdx.x;
    const int r = tid >> 4, tj = tid & 15;
    const u16* srow = Xsrc + (size_t)r * K;
    const unsigned base = (unsigned)(r * K * 2);
    const unsigned swz = (unsigned)((r & 7) << 4);
    constexpr int U = K / 8;   // 16B units per row
    for (int k0 = tj; k0 < U; k0 += 128) {
        bf16x8 t[8];
#pragma unroll
        for (int i = 0; i < 8; ++i) {
            int k = k0 + i * 16;
            if (k < U) ldg16_nt(srow + k * 8, t[i]);
        }
        asm volatile("s_waitcnt vmcnt(0)" ::: "memory");
        __builtin_amdgcn_sched_barrier(0);
#pragma unroll
        for (int i = 0; i < 8; ++i) {
            int k = k0 + i * 16;
            if (k < U)
                *(bf16x8*)((char*)xl + ((base + (unsigned)k * 16u) ^ swz)) = t[i];
        }
    }
}

// ---------------- K-split GRU wave (W: plain L2 loads; X: LDS) ----------
template <int KB0, int KB1, int SPLIT, int K>
__device__ __forceinline__ void gru_wave_lds(
        const u16* __restrict__ W, const u16* __restrict__ xl,
        int j0w, int row,
        f32x4& accR, f32x4& accZ, f32x4& accN0, f32x4& accN1) {
    const int lane = threadIdx.x & 63;
    const int l15 = lane & 15, kq = lane >> 4;
    const u16* Wr = W + (size_t)(j0w + l15) * K + kq * 8;
    const u16* Wz = Wr + (size_t)1024 * K;
    const u16* Wn = Wz + (size_t)1024 * K;
    const unsigned xbase = (unsigned)(row * K * 2 + kq * 16);
    const unsigned swz = (unsigned)((row & 7) << 4);
    accR = (f32x4){0.f, 0.f, 0.f, 0.f};
    accZ = (f32x4){0.f, 0.f, 0.f, 0.f};
    accN0 = (f32x4){0.f, 0.f, 0.f, 0.f};
    accN1 = (f32x4){0.f, 0.f, 0.f, 0.f};
    constexpr int E0 = (SPLIT < KB1) ? SPLIT : KB1;
    constexpr int S1 = (SPLIT > KB0) ? SPLIT : KB0;
#pragma unroll 8
    for (int kb = KB0; kb < E0; ++kb) {
        const int o = kb * 32;
        bf16x8 xb = *(const bf16x8*)((const char*)xl + ((xbase + (unsigned)kb * 64u) ^ swz));
        accR  = mfma16(*(const bf16x8*)(Wr + o), xb, accR);
        accZ  = mfma16(*(const bf16x8*)(Wz + o), xb, accZ);
        accN0 = mfma16(*(const bf16x8*)(Wn + o), xb, accN0);
    }
#pragma unroll 8
    for (int kb = S1; kb < KB1; ++kb) {
        const int o = kb * 32;
        bf16x8 xb = *(const bf16x8*)((const char*)xl + ((xbase + (unsigned)kb * 64u) ^ swz));
        accR  = mfma16(*(const bf16x8*)(Wr + o), xb, accR);
        accZ  = mfma16(*(const bf16x8*)(Wz + o), xb, accZ);
        accN1 = mfma16(*(const bf16x8*)(Wn + o), xb, accN1);
    }
}

// ---------------- WG-level GRU tile: 32 h-rows x 32 batch ----------------
template <int KBT, int SPLIT, int K>
__device__ __forceinline__ void gru_block32(
        const u16* __restrict__ W, const u16* __restrict__ X,
        const float* __restrict__ Hold, const float* __restrict__ Bias,
        int htile, int bq,
        float* __restrict__ Hnew,
        u16* __restrict__ O1, int ld1, int off1,
        u16* __restrict__ O2, int ld2, int off2,
        float* __restrict__ sred /* [4][64][17] */, u16* __restrict__ xl) {
    stage_x<K>(X + (size_t)bq * 32 * K, xl);
    __syncthreads();

    const int tid = threadIdx.x, lane = tid & 63, w = tid >> 6;
    const int hf = w & 1, bf = (w >> 1) & 1, grp = w >> 2, bg = w & 3;
    const int l15 = lane & 15, kq = lane >> 4;
    const int j0w = htile * 32 + hf * 16;
    const int rowl = bf * 16 + l15;
    constexpr int MID = KBT / 2;

    f32x4 aR, aZ, aN0, aN1;
    if (grp == 0) gru_wave_lds<0, MID, SPLIT, K>(W, xl, j0w, rowl, aR, aZ, aN0, aN1);
    else          gru_wave_lds<MID, KBT, SPLIT, K>(W, xl, j0w, rowl, aR, aZ, aN0, aN1);

    float* slot = sred + ((size_t)bg * 64 + lane) * 17;
    if (grp == 1) {
#pragma unroll
        for (int q = 0; q < 4; ++q) {
            slot[q]      = aR[q];
            slot[4 + q]  = aZ[q];
            slot[8 + q]  = aN0[q];
            slot[12 + q] = aN1[q];
        }
    }
    __syncthreads();
    if (grp == 0) {
        const int nb = bq * 32 + bf * 16 + l15;
        float hv4[4];
#pragma unroll
        for (int q = 0; q < 4; ++q) {
            const int j = j0w + kq * 4 + q;
            float R  = aR[q]  + slot[q];
            float Z  = aZ[q]  + slot[4 + q];
            float Nh = aN0[q] + slot[8 + q];
            float Ni = aN1[q] + slot[12 + q];
            float r = 1.f / (1.f + expf(-(R + Bias[j])));
            float z = 1.f / (1.f + expf(-(Z + Bias[1024 + j])));
            float n = tanhf(Ni + Bias[2048 + j] + r * (Nh + Bias[3072 + j]));
            float ho = aldf(&Hold[(size_t)j * Bsz + nb]);
            float hv = (1.f - z) * n + z * ho;
            astf(&Hnew[(size_t)j * Bsz + nb], hv);
            hv4[q] = hv;
        }
        union { u16 h[4]; u64 q8; } pk;
#pragma unroll
        for (int q = 0; q < 4; ++q) pk.h[q] = f2bf(hv4[q]);
        ast64(&O1[(size_t)nb * ld1 + off1 + j0w + kq * 4], pk.q8);
        if (O2) ast64(&O2[(size_t)nb * ld2 + off2 + j0w + kq * 4], pk.q8);
    }
}

// ---------------- params ----------------
struct KParams {
    const float* enc_input;
    const float* dec_input;
    const u16 *W0, *W1, *WD0, *WD1, *WH1, *WH2;
    const float *B0, *B1, *BD0, *BD1, *HB;
    u16 *X0, *X1, *XD0, *XD1, *Hhead, *Abuf;
    float *H0f, *H1f;
    float* out;
    unsigned* bar;
};

// ---------------- round bodies ----------------

__device__ __forceinline__ void enc_L0_round(const KParams& p, int r, int htile, int bq,
                                             float* sred, u16* xl) {
    const int pr = r & 1, pw = pr ^ 1;
    gru_block32<34, 32, K0>(p.W0, p.X0 + pr * SX0, p.H0f + pr * SH, p.B0,
                            htile, bq,
                            p.H0f + pw * SH,
                            p.X0 + pw * SX0, K0, 0,
                            p.X1 + pw * SX1, K1, 1024, sred, xl);
    if (r + 1 < 512 && threadIdx.x < 16) {
        int b = bq * 32 + htile, f4 = threadIdx.x * 4;
        const float* src = p.enc_input + ((size_t)b * TIN + (r + 1)) * INF + f4;
        union { u16 h[4]; u64 q8; } pk;
#pragma unroll
        for (int i = 0; i < 4; ++i) pk.h[i] = f2bf(src[i]);
        ast64(&p.X0[(size_t)pw * SX0 + (size_t)b * K0 + 1024 + f4], pk.q8);
    }
}

__device__ __forceinline__ void enc_L1_step(const KParams& p, int s, int htile, int bq,
                                            float* sred, u16* xl) {
    const int pr = s & 1, pw = pr ^ 1;
    gru_block32<64, 32, K1>(p.W1, p.X1 + pr * SX1, p.H1f + pr * SH, p.B1,
                            htile, bq,
                            p.H1f + pw * SH,
                            p.X1 + pw * SX1, K1, 0,
                            (u16*)nullptr, 0, 0, sred, xl);
}

__device__ __forceinline__ void transition_body(const KParams& p) {
    int gtid = blockIdx.x * blockDim.x + threadIdx.x;
    const int G = 256 * 512;
    for (int i = gtid; i < SH; i += G)
        astf(&p.H1f[i], aldf(&p.H1f[SH + i]));
    for (int i = gtid; i < Bsz * Hdim; i += G) {
        int b = i >> 10, j = i & 1023;
        astu16(&p.XD0[(size_t)b * KD0 + j], aldu16(&p.X0[(size_t)b * K0 + j]));  // eh0 bf16
    }
    for (int i = gtid; i < Bsz * OUTF; i += G) {
        int b = i >> 5, f = i & 31;
        astu16(&p.XD0[(size_t)b * KD0 + 1024 + f],
               f2bf(p.enc_input[((size_t)b * TIN + (TIN - 1)) * INF + f]));
    }
    for (int i = gtid; i < Bsz * INF; i += G) {
        int b = i >> 6, f = i & 63;
        astu16(&p.XD0[(size_t)b * KD0 + 1056 + f],
               f2bf(p.dec_input[(size_t)b * (TOUT * INF) + f]));
    }
    for (int i = gtid; i < Bsz * Hdim; i += G) {
        int b = i >> 10, j = i & 1023;
        astu16(&p.XD1[(size_t)b * KD1 + j],
               aldu16(&p.X1[(size_t)SX1 + (size_t)b * K1 + j]));  // eh1 bf16
    }
}

__device__ __forceinline__ void dec_A_body(const KParams& p, int t, int htile, int bq,
                                           float* sred, u16* xl) {
    const int pt = t & 1, pn = pt ^ 1;
    gru_block32<35, 32, KD0>(p.WD0, p.XD0 + pt * SXD0, p.H0f + pt * SH, p.BD0,
                             htile, bq,
                             p.H0f + pn * SH,
                             p.XD0 + pn * SXD0, KD0, 0,
                             p.XD1 + pt * SXD1, KD1, 1024, sred, xl);
}

__device__ __forceinline__ void dec_B_body(const KParams& p, int t, int htile, int bq,
                                           float* sred, u16* xl) {
    const int pt = t & 1, pn = pt ^ 1;
    gru_block32<64, 32, KD1>(p.WD1, p.XD1 + pt * SXD1, p.H1f + pt * SH, p.BD1,
                             htile, bq,
                             p.H1f + pn * SH,
                             p.XD1 + pn * SXD1, KD1, 0,
                             p.Hhead, KH, 0, sred, xl);
}

// a = relu(h1 @ W1^T + b); stage x_{t+1} (group-local row).
__device__ __forceinline__ void dec_C_body(const KParams& p, int t, int htile, int bq,
                                           float* sred, u16* xl) {
    const int pn = (t & 1) ^ 1;
    stage_x<KH>(p.Hhead + (size_t)bq * 32 * KH, xl);
    __syncthreads();

    const int tid = threadIdx.x, lane = tid & 63, w = tid >> 6;
    const int hf = w & 1, bf = (w >> 1) & 1, grp = w >> 2, bg = w & 3;
    const int l15 = lane & 15, kq = lane >> 4;
    const int j0w = htile * 32 + hf * 16;
    const int rowl = bf * 16 + l15;

    const u16* Wr = p.WH1 + (size_t)(j0w + l15) * KH + kq * 8;
    const unsigned xbase = (unsigned)(rowl * KH * 2 + kq * 16);
    const unsigned swz = (unsigned)((rowl & 7) << 4);
    f32x4 acc = {0.f, 0.f, 0.f, 0.f};
    const int kb0 = grp * 16, kb1 = kb0 + 16;
#pragma unroll 8
    for (int kb = kb0; kb < kb1; ++kb) {
        bf16x8 xb = *(const bf16x8*)((const char*)xl + ((xbase + (unsigned)kb * 64u) ^ swz));
        acc = mfma16(*(const bf16x8*)(Wr + kb * 32), xb, acc);
    }
    float* slot = sred + ((size_t)bg * 64 + lane) * 17;
    if (grp == 1) {
#pragma unroll
        for (int q = 0; q < 4; ++q) slot[q] = acc[q];
    }
    __syncthreads();
    if (grp == 0) {
        const int nb = bq * 32 + bf * 16 + l15;
        union { u16 h[4]; u64 q8; } pk;
#pragma unroll
        for (int q = 0; q < 4; ++q) {
            const int j = j0w + kq * 4 + q;
            float v = acc[q] + slot[q] + p.HB[j];
            pk.h[q] = f2bf(v > 0.f ? v : 0.f);
        }
        ast64(&p.Abuf[(size_t)nb * KH + j0w + kq * 4], pk.q8);
    }
    if (t + 1 < TOUT && tid < 16) {
        int b = bq * 32 + htile, f4 = tid * 4;
        const float* src = p.dec_input + ((size_t)b * TOUT + (t + 1)) * INF + f4;
        union { u16 h[4]; u64 q8; } pk2;
#pragma unroll
        for (int i = 0; i < 4; ++i) pk2.h[i] = f2bf(src[i]);
        ast64(&p.XD0[(size_t)pn * SXD0 + (size_t)b * KD0 + 1056 + f4], pk2.q8);
    }
}

// out = a @ W2^T: 4 blocks per bq (htile<4), mt=htile&1, ntl=htile>>1.
__device__ __forceinline__ void dec_D_body(const KParams& p, int t, int htile, int bq,
                                           float* sred) {
    const int pn = (t & 1) ^ 1;
    const int tid = threadIdx.x, lane = tid & 63, w = tid >> 6;
    const int l15 = lane & 15, kq = lane >> 4;
    const int mt = htile & 1, ntl = htile >> 1;
    const int brow = bq * 32 + ntl * 16;
    if (w < 4) {
        const u16* Wr = p.WH2 + (size_t)(mt * 16 + l15) * KH + kq * 8;
        const u16* Xb = p.Abuf + (size_t)(brow + l15) * KH + kq * 8;
        f32x4 acc = {0.f, 0.f, 0.f, 0.f};
#pragma unroll 8
        for (int kb = w * 8; kb < w * 8 + 8; ++kb) {
            const int o = kb * 32;
            acc = mfma16(*(const bf16x8*)(Wr + o), ldx(Xb + o), acc);
        }
#pragma unroll
        for (int q = 0; q < 4; ++q) sred[(w * 64 + lane) * 4 + q] = acc[q];
    }
    __syncthreads();
    if (w == 0) {
        int b = brow + l15;
        union { u16 h[4]; u64 q8; } pk;
#pragma unroll
        for (int q = 0; q < 4; ++q) {
            float s = sred[(0 * 64 + lane) * 4 + q] + sred[(1 * 64 + lane) * 4 + q] +
                      sred[(2 * 64 + lane) * 4 + q] + sred[(3 * 64 + lane) * 4 + q];
            int feat = mt * 16 + kq * 4 + q;
            p.out[(size_t)b * (TOUT * OUTF) + t * OUTF + feat] = s;
            pk.h[q] = f2bf(s);
        }
        ast64(&p.XD0[(size_t)pn * SXD0 + (size_t)b * KD0 + 1024 + mt * 16 + kq * 4], pk.q8);
    }
}

// ---------------- the persistent kernel (group-pipelined) ----------------
// Groups: L0:bq(0-3), L1:4+bq, decA:8+bq, decB:12+bq, decC:16+bq, decD:20+bq.
__global__ void __launch_bounds__(512, 1) seq2seq_persist(KParams p) {
    __shared__ float sred[4 * 64 * 17];          // 17.4 KB
    __shared__ u16 xls[32 * 2048];               // 128 KB staged X slab
    unsigned* bar = p.bar;
    const int wg = blockIdx.x;

    // ======== encoder: L0 and L1 pipelines, group-local sync ========
    if (wg < 128) {
        int htile, bq; tile_map32(wg, htile, bq);
        unsigned* arrL0 = grp_arr(bar, bq);
        unsigned* genL0 = grp_gen(bar, bq);
        unsigned* genL1 = grp_gen(bar, 4 + bq);
        for (int r = 0; r < 512; ++r) {
            // L0 round r overwrites X1 parity read by L1 step r-1
            if (r >= 2) waitgen(genL1, (unsigned)(r - 1));
            enc_L0_round(p, r, htile, bq, sred, xls);
            groupbar<32>(arrL0, genL0, (unsigned)(r + 1));
        }
    } else {
        int htile, bq; tile_map32(wg - 128, htile, bq);
        unsigned* arrL1 = grp_arr(bar, 4 + bq);
        unsigned* genL1 = grp_gen(bar, 4 + bq);
        unsigned* genL0 = grp_gen(bar, bq);
        for (int s = 1; s <= 512; ++s) {
            waitgen(genL0, (unsigned)s);   // L0 rounds 0..s-1 complete
            enc_L1_step(p, s, htile, bq, sred, xls);
            groupbar<32>(arrL1, genL1, (unsigned)s);
        }
    }

    // ======== transition (global) ========
    gridbar(bar, 1);
    transition_body(p);
    gridbar(bar, 2);

    // ======== decoder: 4 independent bq pipelines ========
    if (wg < 128) {
        int htile, bq; tile_map32(wg, htile, bq);
        unsigned* arrA = grp_arr(bar, 8 + bq);  unsigned* genA = grp_gen(bar, 8 + bq);
        unsigned* arrB = grp_arr(bar, 12 + bq); unsigned* genB = grp_gen(bar, 12 + bq);
        unsigned* arrC = grp_arr(bar, 16 + bq); unsigned* genC = grp_gen(bar, 16 + bq);
        unsigned* arrD = grp_arr(bar, 20 + bq); unsigned* genD = grp_gen(bar, 20 + bq);
        for (int t = 0; t < TOUT; ++t) {
            if (t >= 1) waitgen(genD, (unsigned)t);   // yp from D of step t-1
            dec_A_body(p, t, htile, bq, sred, xls);
            groupbar<32>(arrA, genA, (unsigned)(t + 1));
            dec_B_body(p, t, htile, bq, sred, xls);
            groupbar<32>(arrB, genB, (unsigned)(t + 1));
            dec_C_body(p, t, htile, bq, sred, xls);
            groupbar<32>(arrC, genC, (unsigned)(t + 1));
            if (htile < 4) {
                dec_D_body(p, t, htile, bq, sred);
                groupbar<4>(arrD, genD, (unsigned)(t + 1));
            }
        }
    }
}

// ---------------- host launch ----------------
extern "C" void kernel_launch(void* const* d_in, const int* in_sizes, int n_in,
                              void* d_out, int out_size, void* d_ws, size_t ws_size,
                              hipStream_t stream) {
    const float* enc_input = (const float*)d_in[0];
    const float* dec_input = (const float*)d_in[1];
    const float* enc_Wih0 = (const float*)d_in[2];
    const float* enc_Whh0 = (const float*)d_in[3];
    const float* enc_bih0 = (const float*)d_in[4];
    const float* enc_bhh0 = (const float*)d_in[5];
    const float* enc_Wih1 = (const float*)d_in[6];
    const float* enc_Whh1 = (const float*)d_in[7];
    const float* enc_bih1 = (const float*)d_in[8];
    const float* enc_bhh1 = (const float*)d_in[9];
    const float* dec_Wih0 = (const float*)d_in[10];
    const float* dec_Whh0 = (const float*)d_in[11];
    const float* dec_bih0 = (const float*)d_in[12];
    const float* dec_bhh0 = (const float*)d_in[13];
    const float* dec_Wih1 = (const float*)d_in[14];
    const float* dec_Whh1 = (const float*)d_in[15];
    const float* dec_bih1 = (const float*)d_in[16];
    const float* dec_bhh1 = (const float*)d_in[17];
    const float* out1_W = (const float*)d_in[18];
    const float* out1_b = (const float*)d_in[19];
    const float* out2_W = (const float*)d_in[20];

    char* ws = (char*)d_ws;
    size_t off = 0;
    auto alloc = [&](size_t bytes) { size_t o = off; off = (off + bytes + 255) & ~(size_t)255; return o; };

    u16* W0 = (u16*)(ws + alloc((size_t)H3 * K0 * 2));
    u16* W1 = (u16*)(ws + alloc((size_t)H3 * K1 * 2));
    u16* WD0 = (u16*)(ws + alloc((size_t)H3 * KD0 * 2));
    u16* WD1 = (u16*)(ws + alloc((size_t)H3 * KD1 * 2));
    u16* WH1 = (u16*)(ws + alloc((size_t)Hdim * KH * 2));
    u16* WH2 = (u16*)(ws + alloc((size_t)OUTF * KH * 2));
    float* B0 = (float*)(ws + alloc(4096 * 4));
    float* B1 = (float*)(ws + alloc(4096 * 4));
    float* BD0 = (float*)(ws + alloc(4096 * 4));
    float* BD1 = (float*)(ws + alloc(4096 * 4));
    float* HB = (float*)(ws + alloc(1024 * 4));
    u16* X0 = (u16*)(ws + alloc((size_t)2 * Bsz * K0 * 2));
    u16* X1 = (u16*)(ws + alloc((size_t)2 * Bsz * K1 * 2));
    u16* XD0 = (u16*)(ws + alloc((size_t)2 * Bsz * KD0 * 2));
    u16* XD1 = (u16*)(ws + alloc((size_t)2 * Bsz * KD1 * 2));
    float* H0f = (float*)(ws + alloc((size_t)2 * Bsz * Hdim * 4));
    float* H1f = (float*)(ws + alloc((size_t)2 * Bsz * Hdim * 4));
    u16* Hhead = (u16*)(ws + alloc((size_t)Bsz * KH * 2));
    u16* Abuf = (u16*)(ws + alloc((size_t)Bsz * KH * 2));
    unsigned* bar = (unsigned*)(ws + alloc(BAR_WORDS * 4));

    // --- prologue: weight/bias repack (h-part FIRST) + state/barrier init ---
    pack2<<<dim3((K0 + 255) / 256, H3), 256, 0, stream>>>(enc_Whh0, 1024, enc_Wih0, 64, W0);
    pack2<<<dim3((K1 + 255) / 256, H3), 256, 0, stream>>>(enc_Whh1, 1024, enc_Wih1, 1024, W1);
    pack2<<<dim3((KD0 + 255) / 256, H3), 256, 0, stream>>>(dec_Whh0, 1024, dec_Wih0, 96, WD0);
    pack2<<<dim3((KD1 + 255) / 256, H3), 256, 0, stream>>>(dec_Whh1, 1024, dec_Wih1, 1024, WD1);
    pack2<<<dim3((KH + 255) / 256, Hdim), 256, 0, stream>>>(out1_W, 1024, nullptr, 0, WH1);
    pack2<<<dim3((KH + 255) / 256, OUTF), 256, 0, stream>>>(out2_W, 1024, nullptr, 0, WH2);
    pack_bias<<<4, 256, 0, stream>>>(enc_bih0, enc_bhh0, enc_bih1, enc_bhh1,
                                     dec_bih0, dec_bhh0, dec_bih1, dec_bhh1,
                                     out1_b, B0, B1, BD0, BD1, HB);
    init_state<<<256, 256, 0, stream>>>(enc_input, X0, X1, H0f, H1f, bar);

    KParams kp;
    kp.enc_input = enc_input; kp.dec_input = dec_input;
    kp.W0 = W0; kp.W1 = W1; kp.WD0 = WD0; kp.WD1 = WD1; kp.WH1 = WH1; kp.WH2 = WH2;
    kp.B0 = B0; kp.B1 = B1; kp.BD0 = BD0; kp.BD1 = BD1; kp.HB = HB;
    kp.X0 = X0; kp.X1 = X1; kp.XD0 = XD0; kp.XD1 = XD1; kp.Hhead = Hhead; kp.Abuf = Abuf;
    kp.H0f = H0f; kp.H1f = H1f;
    kp.out = (float*)d_out;
    kp.bar = bar;

    seq2seq_persist<<<256, 512, 0, stream>>>(kp);
}

// Round 9
// 21700.136 us; speedup vs baseline: 2.8000x; 1.0025x over previous
//
#include <hip/hip_runtime.h>

typedef unsigned short u16;
typedef unsigned long long u64;
typedef __attribute__((ext_vector_type(8))) short bf16x8;
typedef __attribute__((ext_vector_type(4))) float f32x4;

// ---------------- constants ----------------
#define Bsz   128
#define TIN   512
#define TOUT  64
#define INF   64
#define OUTF  32
#define Hdim  1024
#define H3    3072

// K layouts: H-PART FIRST everywhere (uniform n-gate split at kb=32)
#define K0    1088   // enc L0: [h(1024) | x(64)]
#define K1    2048   // enc L1: [h1(1024) | y0(1024)]
#define KD0   1120   // dec L0: [h(1024) | yp(32) x(64)]
#define KD1   2048   // dec L1: [h1(1024) | h0(1024)]
#define KH    1024

#define SX0  (Bsz * K0)
#define SX1  (Bsz * K1)
#define SXD0 (Bsz * KD0)
#define SXD1 (Bsz * KD1)
#define SH   (Bsz * Hdim)

// barrier words: global barrier uses 0..543; group counters at 1024 + g*32.
#define BAR_ROOT 512
#define BAR_GEN  528
#define GRP_BASE 1024
#define BAR_WORDS 2048

__device__ __forceinline__ u16 f2bf(float f) {
    union { float f; unsigned u; } c; c.f = f;
    unsigned u = c.u;
    unsigned r = (u + 0x7fffu + ((u >> 16) & 1u)) >> 16;
    return (u16)r;
}

__device__ __forceinline__ f32x4 mfma16(bf16x8 a, bf16x8 b, f32x4 c) {
    return __builtin_amdgcn_mfma_f32_16x16x32_bf16(a, b, c, 0, 0, 0);
}

// XCD-aware tile map (unchanged from R8).
__device__ __forceinline__ void tile_map32(int wg, int& htile, int& bq) {
    const int xcd = wg & 7, idx = wg >> 3;
    htile = ((idx & 3) << 3) + xcd;   // 0..31
    bq = idx >> 2;                    // 0..3
}

// ---------- agent-coherent (IF$-level) state accessors ----------
__device__ __forceinline__ u64 ald64(const void* p) {
    return __hip_atomic_load((const u64*)p, __ATOMIC_RELAXED, __HIP_MEMORY_SCOPE_AGENT);
}
__device__ __forceinline__ void ast64(void* p, u64 v) {
    __hip_atomic_store((u64*)p, v, __ATOMIC_RELAXED, __HIP_MEMORY_SCOPE_AGENT);
}
__device__ __forceinline__ float aldf(const float* p) {
    return __hip_atomic_load(p, __ATOMIC_RELAXED, __HIP_MEMORY_SCOPE_AGENT);
}
__device__ __forceinline__ void astf(float* p, float v) {
    __hip_atomic_store(p, v, __ATOMIC_RELAXED, __HIP_MEMORY_SCOPE_AGENT);
}
__device__ __forceinline__ u16 aldu16(const u16* p) {
    return __hip_atomic_load(p, __ATOMIC_RELAXED, __HIP_MEMORY_SCOPE_AGENT);
}
__device__ __forceinline__ void astu16(u16* p, u16 v) {
    __hip_atomic_store(p, v, __ATOMIC_RELAXED, __HIP_MEMORY_SCOPE_AGENT);
}
__device__ __forceinline__ bf16x8 ldx(const u16* p) {
    union { u64 q[2]; bf16x8 v; } u;
    u.q[0] = ald64(p);
    u.q[1] = ald64(p + 4);
    return u.v;
}

// 16B coherent non-temporal load (state staging).
__device__ __forceinline__ void ldg16_nt(const u16* p, bf16x8& v) {
    asm volatile("global_load_dwordx4 %0, %1, off sc0 sc1 nt"
                 : "=&v"(v) : "v"(p));
}

// ---------------- sync primitives (unchanged from R8) ----------------
template <unsigned NB>
__device__ __forceinline__ void groupbar(unsigned* arr, unsigned* gen, unsigned target) {
    __syncthreads();
    if (threadIdx.x == 0) {
        asm volatile("s_waitcnt vmcnt(0) lgkmcnt(0)" ::: "memory");
        unsigned a = __hip_atomic_fetch_add(arr, 1u,
                        __ATOMIC_RELAXED, __HIP_MEMORY_SCOPE_AGENT);
        if (((a + 1u) & (NB - 1u)) == 0u)
            __hip_atomic_fetch_add(gen, 1u,
                        __ATOMIC_RELAXED, __HIP_MEMORY_SCOPE_AGENT);
        while (__hip_atomic_load(gen, __ATOMIC_RELAXED, __HIP_MEMORY_SCOPE_AGENT) < target)
            __builtin_amdgcn_s_sleep(2);
        asm volatile("" ::: "memory");
    }
    __syncthreads();
}

__device__ __forceinline__ void waitgen(unsigned* gen, unsigned target) {
    if (threadIdx.x == 0) {
        while (__hip_atomic_load(gen, __ATOMIC_RELAXED, __HIP_MEMORY_SCOPE_AGENT) < target)
            __builtin_amdgcn_s_sleep(2);
        asm volatile("" ::: "memory");
    }
    __syncthreads();
}

__device__ __forceinline__ void gridbar(unsigned* bar, unsigned target) {
    __syncthreads();
    if (threadIdx.x == 0) {
        asm volatile("s_waitcnt vmcnt(0) lgkmcnt(0)" ::: "memory");
        unsigned leaf = (blockIdx.x >> 3) << 4;
        unsigned a = __hip_atomic_fetch_add(&bar[leaf], 1u,
                        __ATOMIC_RELAXED, __HIP_MEMORY_SCOPE_AGENT);
        if (((a + 1u) & 7u) == 0u) {
            unsigned r = __hip_atomic_fetch_add(&bar[BAR_ROOT], 1u,
                            __ATOMIC_RELAXED, __HIP_MEMORY_SCOPE_AGENT);
            if (((r + 1u) & 31u) == 0u)
                __hip_atomic_fetch_add(&bar[BAR_GEN], 1u,
                        __ATOMIC_RELAXED, __HIP_MEMORY_SCOPE_AGENT);
        }
        while (__hip_atomic_load(&bar[BAR_GEN],
                    __ATOMIC_RELAXED, __HIP_MEMORY_SCOPE_AGENT) < target)
            __builtin_amdgcn_s_sleep(2);
        asm volatile("" ::: "memory");
    }
    __syncthreads();
}

__device__ __forceinline__ unsigned* grp_arr(unsigned* bar, int g) { return bar + GRP_BASE + g * 32; }
__device__ __forceinline__ unsigned* grp_gen(unsigned* bar, int g) { return bar + GRP_BASE + g * 32 + 16; }

// ---------------- prologue kernels ----------------

// Fragment-major weight retile: dst flat index
//   idx = ((((htile*KBT + kb)*2 + hf)*G + g)*64 + lane)*8 + e
// maps to source row = g*1024 + htile*32 + hf*16 + (lane&15),
//           col = kb*32 + (lane>>4)*8 + e, col<KA from A (W_hh) else B (W_ih).
// Result: each wave's per-kb loads are 3 contiguous 1 KB blocks, sequential
// across kb -> no L2 channel aliasing (was 4 KB row stride).
__global__ void __launch_bounds__(256) pack_tiled(
        const float* __restrict__ A, int KA,
        const float* __restrict__ Bs, int KB,
        u16* __restrict__ dst, int KBT, int G) {
    long idx = (long)blockIdx.x * 256 + threadIdx.x;
    long total = (long)32 * KBT * 2 * G * 512;
    if (idx >= total) return;
    int e = (int)(idx & 7);
    int lane = (int)((idx >> 3) & 63);
    long r1 = idx >> 9;
    int g = (int)(r1 % G);
    long r2 = r1 / G;
    int hf = (int)(r2 & 1);
    long r3 = r2 >> 1;
    int kb = (int)(r3 % KBT);
    int htile = (int)(r3 / KBT);
    int row = g * 1024 + htile * 32 + hf * 16 + (lane & 15);
    int col = kb * 32 + (lane >> 4) * 8 + e;
    float v = (col < KA) ? A[(size_t)row * KA + col]
                         : Bs[(size_t)row * KB + (col - KA)];
    dst[idx] = f2bf(v);
}

// WH2 keeps row-major (small, dec_D only).
__global__ void __launch_bounds__(256) pack2(
        const float* __restrict__ A, int KA,
        const float* __restrict__ Bs, int KB,
        u16* __restrict__ dst) {
    int row = blockIdx.y;
    int k = blockIdx.x * 256 + threadIdx.x;
    int K = KA + KB;
    if (k >= K) return;
    float v = (k < KA) ? A[(size_t)row * KA + k] : Bs[(size_t)row * KB + (k - KA)];
    dst[(size_t)row * K + k] = f2bf(v);
}

__global__ void __launch_bounds__(256) pack_bias(
        const float* bi0e, const float* bh0e,
        const float* bi1e, const float* bh1e,
        const float* bi0d, const float* bh0d,
        const float* bi1d, const float* bh1d,
        const float* out1b,
        float* B0, float* B1, float* BD0, float* BD1, float* HB) {
    int j = blockIdx.x * blockDim.x + threadIdx.x;
    if (j >= 1024) return;
    const float* bis[4] = { bi0e, bi1e, bi0d, bi1d };
    const float* bhs[4] = { bh0e, bh1e, bh0d, bh1d };
    float* ds[4] = { B0, B1, BD0, BD1 };
#pragma unroll
    for (int s = 0; s < 4; ++s) {
        ds[s][j]        = bis[s][j]        + bhs[s][j];
        ds[s][1024 + j] = bis[s][1024 + j] + bhs[s][1024 + j];
        ds[s][2048 + j] = bis[s][2048 + j];
        ds[s][3072 + j] = bhs[s][2048 + j];
    }
    HB[j] = out1b[j];
}

__global__ void __launch_bounds__(256) init_state(
        const float* __restrict__ enc_input,
        u16* __restrict__ X0, u16* __restrict__ X1,
        float* __restrict__ H0f, float* __restrict__ H1f,
        unsigned* __restrict__ bar) {
    int gtid = blockIdx.x * blockDim.x + threadIdx.x;
    int G = gridDim.x * blockDim.x;
    for (int i = gtid; i < BAR_WORDS; i += G) bar[i] = 0u;
    for (int i = gtid; i < Bsz * Hdim; i += G) { int b = i >> 10, j = i & 1023; X0[(size_t)b * K0 + j] = 0; }
    for (int i = gtid; i < Bsz * INF; i += G) { int b = i >> 6, f = i & 63;
        X0[(size_t)b * K0 + 1024 + f] = f2bf(enc_input[(size_t)b * (TIN * INF) + f]); }
    for (int i = gtid; i < Bsz * Hdim; i += G) { int b = i >> 10, j = i & 1023;
        X1[(size_t)SX1 + (size_t)b * K1 + j] = 0; }
    for (int i = gtid; i < Bsz * Hdim; i += G) { H0f[i] = 0.f; H1f[SH + i] = 0.f; }
}

// ---------------- LDS X staging (unchanged from R8) ----------------
template <int K>
__device__ __forceinline__ void stage_x(const u16* __restrict__ Xsrc, u16* __restrict__ xl) {
    const int tid = threadIdx.x;
    const int r = tid >> 4, tj = tid & 15;
    const u16* srow = Xsrc + (size_t)r * K;
    const unsigned base = (unsigned)(r * K * 2);
    const unsigned swz = (unsigned)((r & 7) << 4);
    constexpr int U = K / 8;
    for (int k0 = tj; k0 < U; k0 += 128) {
        bf16x8 t[8];
#pragma unroll
        for (int i = 0; i < 8; ++i) {
            int k = k0 + i * 16;
            if (k < U) ldg16_nt(srow + k * 8, t[i]);
        }
        asm volatile("s_waitcnt vmcnt(0)" ::: "memory");
        __builtin_amdgcn_sched_barrier(0);
#pragma unroll
        for (int i = 0; i < 8; ++i) {
            int k = k0 + i * 16;
            if (k < U)
                *(bf16x8*)((char*)xl + ((base + (unsigned)k * 16u) ^ swz)) = t[i];
        }
    }
}

// ---------------- K-split GRU wave (W: tiled contiguous stream) ----------
// W address: htile*KBT*3072 + hf*1536 + lane*8  + kb*3072 + g*512.
template <int KB0, int KB1, int SPLIT, int K, int KBT>
__device__ __forceinline__ void gru_wave_lds(
        const u16* __restrict__ W, const u16* __restrict__ xl,
        int htile, int hf, int row,
        f32x4& accR, f32x4& accZ, f32x4& accN0, f32x4& accN1) {
    const int lane = threadIdx.x & 63;
    const int kq = lane >> 4;
    const u16* Wl = W + (size_t)htile * KBT * 3072 + hf * 1536 + lane * 8;
    const unsigned xbase = (unsigned)(row * K * 2 + kq * 16);
    const unsigned swz = (unsigned)((row & 7) << 4);
    accR = (f32x4){0.f, 0.f, 0.f, 0.f};
    accZ = (f32x4){0.f, 0.f, 0.f, 0.f};
    accN0 = (f32x4){0.f, 0.f, 0.f, 0.f};
    accN1 = (f32x4){0.f, 0.f, 0.f, 0.f};
    constexpr int E0 = (SPLIT < KB1) ? SPLIT : KB1;
    constexpr int S1 = (SPLIT > KB0) ? SPLIT : KB0;
#pragma unroll 8
    for (int kb = KB0; kb < E0; ++kb) {
        const u16* wk = Wl + (size_t)kb * 3072;
        bf16x8 xb = *(const bf16x8*)((const char*)xl + ((xbase + (unsigned)kb * 64u) ^ swz));
        accR  = mfma16(*(const bf16x8*)(wk), xb, accR);
        accZ  = mfma16(*(const bf16x8*)(wk + 512), xb, accZ);
        accN0 = mfma16(*(const bf16x8*)(wk + 1024), xb, accN0);
    }
#pragma unroll 8
    for (int kb = S1; kb < KB1; ++kb) {
        const u16* wk = Wl + (size_t)kb * 3072;
        bf16x8 xb = *(const bf16x8*)((const char*)xl + ((xbase + (unsigned)kb * 64u) ^ swz));
        accR  = mfma16(*(const bf16x8*)(wk), xb, accR);
        accZ  = mfma16(*(const bf16x8*)(wk + 512), xb, accZ);
        accN1 = mfma16(*(const bf16x8*)(wk + 1024), xb, accN1);
    }
}

// ---------------- WG-level GRU tile: 32 h-rows x 32 batch ----------------
template <int KBT, int SPLIT, int K>
__device__ __forceinline__ void gru_block32(
        const u16* __restrict__ W, const u16* __restrict__ X,
        const float* __restrict__ Hold, const float* __restrict__ Bias,
        int htile, int bq,
        float* __restrict__ Hnew,
        u16* __restrict__ O1, int ld1, int off1,
        u16* __restrict__ O2, int ld2, int off2,
        float* __restrict__ sred /* [4][64][17] */, u16* __restrict__ xl) {
    stage_x<K>(X + (size_t)bq * 32 * K, xl);
    __syncthreads();

    const int tid = threadIdx.x, lane = tid & 63, w = tid >> 6;
    const int hf = w & 1, bf = (w >> 1) & 1, grp = w >> 2, bg = w & 3;
    const int l15 = lane & 15, kq = lane >> 4;
    const int j0w = htile * 32 + hf * 16;
    const int rowl = bf * 16 + l15;

    f32x4 aR, aZ, aN0, aN1;
    if (grp == 0) gru_wave_lds<0, KBT / 2, SPLIT, K, KBT>(W, xl, htile, hf, rowl, aR, aZ, aN0, aN1);
    else          gru_wave_lds<KBT / 2, KBT, SPLIT, K, KBT>(W, xl, htile, hf, rowl, aR, aZ, aN0, aN1);

    float* slot = sred + ((size_t)bg * 64 + lane) * 17;
    if (grp == 1) {
#pragma unroll
        for (int q = 0; q < 4; ++q) {
            slot[q]      = aR[q];
            slot[4 + q]  = aZ[q];
            slot[8 + q]  = aN0[q];
            slot[12 + q] = aN1[q];
        }
    }
    __syncthreads();
    if (grp == 0) {
        const int nb = bq * 32 + bf * 16 + l15;
        float hv4[4];
#pragma unroll
        for (int q = 0; q < 4; ++q) {
            const int j = j0w + kq * 4 + q;
            float R  = aR[q]  + slot[q];
            float Z  = aZ[q]  + slot[4 + q];
            float Nh = aN0[q] + slot[8 + q];
            float Ni = aN1[q] + slot[12 + q];
            float r = 1.f / (1.f + expf(-(R + Bias[j])));
            float z = 1.f / (1.f + expf(-(Z + Bias[1024 + j])));
            float n = tanhf(Ni + Bias[2048 + j] + r * (Nh + Bias[3072 + j]));
            float ho = aldf(&Hold[(size_t)j * Bsz + nb]);
            float hv = (1.f - z) * n + z * ho;
            astf(&Hnew[(size_t)j * Bsz + nb], hv);
            hv4[q] = hv;
        }
        union { u16 h[4]; u64 q8; } pk;
#pragma unroll
        for (int q = 0; q < 4; ++q) pk.h[q] = f2bf(hv4[q]);
        ast64(&O1[(size_t)nb * ld1 + off1 + j0w + kq * 4], pk.q8);
        if (O2) ast64(&O2[(size_t)nb * ld2 + off2 + j0w + kq * 4], pk.q8);
    }
}

// ---------------- params ----------------
struct KParams {
    const float* enc_input;
    const float* dec_input;
    const u16 *W0, *W1, *WD0, *WD1, *WH1, *WH2;
    const float *B0, *B1, *BD0, *BD1, *HB;
    u16 *X0, *X1, *XD0, *XD1, *Hhead, *Abuf;
    float *H0f, *H1f;
    float* out;
    unsigned* bar;
};

// ---------------- round bodies ----------------

__device__ __forceinline__ void enc_L0_round(const KParams& p, int r, int htile, int bq,
                                             float* sred, u16* xl) {
    const int pr = r & 1, pw = pr ^ 1;
    gru_block32<34, 32, K0>(p.W0, p.X0 + pr * SX0, p.H0f + pr * SH, p.B0,
                            htile, bq,
                            p.H0f + pw * SH,
                            p.X0 + pw * SX0, K0, 0,
                            p.X1 + pw * SX1, K1, 1024, sred, xl);
    if (r + 1 < 512 && threadIdx.x < 16) {
        int b = bq * 32 + htile, f4 = threadIdx.x * 4;
        const float* src = p.enc_input + ((size_t)b * TIN + (r + 1)) * INF + f4;
        union { u16 h[4]; u64 q8; } pk;
#pragma unroll
        for (int i = 0; i < 4; ++i) pk.h[i] = f2bf(src[i]);
        ast64(&p.X0[(size_t)pw * SX0 + (size_t)b * K0 + 1024 + f4], pk.q8);
    }
}

__device__ __forceinline__ void enc_L1_step(const KParams& p, int s, int htile, int bq,
                                            float* sred, u16* xl) {
    const int pr = s & 1, pw = pr ^ 1;
    gru_block32<64, 32, K1>(p.W1, p.X1 + pr * SX1, p.H1f + pr * SH, p.B1,
                            htile, bq,
                            p.H1f + pw * SH,
                            p.X1 + pw * SX1, K1, 0,
                            (u16*)nullptr, 0, 0, sred, xl);
}

__device__ __forceinline__ void transition_body(const KParams& p) {
    int gtid = blockIdx.x * blockDim.x + threadIdx.x;
    const int G = 256 * 512;
    for (int i = gtid; i < SH; i += G)
        astf(&p.H1f[i], aldf(&p.H1f[SH + i]));
    for (int i = gtid; i < Bsz * Hdim; i += G) {
        int b = i >> 10, j = i & 1023;
        astu16(&p.XD0[(size_t)b * KD0 + j], aldu16(&p.X0[(size_t)b * K0 + j]));  // eh0 bf16
    }
    for (int i = gtid; i < Bsz * OUTF; i += G) {
        int b = i >> 5, f = i & 31;
        astu16(&p.XD0[(size_t)b * KD0 + 1024 + f],
               f2bf(p.enc_input[((size_t)b * TIN + (TIN - 1)) * INF + f]));
    }
    for (int i = gtid; i < Bsz * INF; i += G) {
        int b = i >> 6, f = i & 63;
        astu16(&p.XD0[(size_t)b * KD0 + 1056 + f],
               f2bf(p.dec_input[(size_t)b * (TOUT * INF) + f]));
    }
    for (int i = gtid; i < Bsz * Hdim; i += G) {
        int b = i >> 10, j = i & 1023;
        astu16(&p.XD1[(size_t)b * KD1 + j],
               aldu16(&p.X1[(size_t)SX1 + (size_t)b * K1 + j]));  // eh1 bf16
    }
}

__device__ __forceinline__ void dec_A_body(const KParams& p, int t, int htile, int bq,
                                           float* sred, u16* xl) {
    const int pt = t & 1, pn = pt ^ 1;
    gru_block32<35, 32, KD0>(p.WD0, p.XD0 + pt * SXD0, p.H0f + pt * SH, p.BD0,
                             htile, bq,
                             p.H0f + pn * SH,
                             p.XD0 + pn * SXD0, KD0, 0,
                             p.XD1 + pt * SXD1, KD1, 1024, sred, xl);
}

__device__ __forceinline__ void dec_B_body(const KParams& p, int t, int htile, int bq,
                                           float* sred, u16* xl) {
    const int pt = t & 1, pn = pt ^ 1;
    gru_block32<64, 32, KD1>(p.WD1, p.XD1 + pt * SXD1, p.H1f + pt * SH, p.BD1,
                             htile, bq,
                             p.H1f + pn * SH,
                             p.XD1 + pn * SXD1, KD1, 0,
                             p.Hhead, KH, 0, sred, xl);
}

// a = relu(h1 @ W1^T + b); WH1 in tiled layout [htile][kb][hf][64][8].
__device__ __forceinline__ void dec_C_body(const KParams& p, int t, int htile, int bq,
                                           float* sred, u16* xl) {
    const int pn = (t & 1) ^ 1;
    stage_x<KH>(p.Hhead + (size_t)bq * 32 * KH, xl);
    __syncthreads();

    const int tid = threadIdx.x, lane = tid & 63, w = tid >> 6;
    const int hf = w & 1, bf = (w >> 1) & 1, grp = w >> 2, bg = w & 3;
    const int l15 = lane & 15, kq = lane >> 4;
    const int j0w = htile * 32 + hf * 16;
    const int rowl = bf * 16 + l15;

    const u16* Wl = p.WH1 + (size_t)htile * 32768 + hf * 512 + lane * 8;
    const unsigned xbase = (unsigned)(rowl * KH * 2 + kq * 16);
    const unsigned swz = (unsigned)((rowl & 7) << 4);
    f32x4 acc = {0.f, 0.f, 0.f, 0.f};
    const int kb0 = grp * 16, kb1 = kb0 + 16;
#pragma unroll 8
    for (int kb = kb0; kb < kb1; ++kb) {
        bf16x8 xb = *(const bf16x8*)((const char*)xl + ((xbase + (unsigned)kb * 64u) ^ swz));
        acc = mfma16(*(const bf16x8*)(Wl + (size_t)kb * 1024), xb, acc);
    }
    float* slot = sred + ((size_t)bg * 64 + lane) * 17;
    if (grp == 1) {
#pragma unroll
        for (int q = 0; q < 4; ++q) slot[q] = acc[q];
    }
    __syncthreads();
    if (grp == 0) {
        const int nb = bq * 32 + bf * 16 + l15;
        union { u16 h[4]; u64 q8; } pk;
#pragma unroll
        for (int q = 0; q < 4; ++q) {
            const int j = j0w + kq * 4 + q;
            float v = acc[q] + slot[q] + p.HB[j];
            pk.h[q] = f2bf(v > 0.f ? v : 0.f);
        }
        ast64(&p.Abuf[(size_t)nb * KH + j0w + kq * 4], pk.q8);
    }
    if (t + 1 < TOUT && tid < 16) {
        int b = bq * 32 + htile, f4 = tid * 4;
        const float* src = p.dec_input + ((size_t)b * TOUT + (t + 1)) * INF + f4;
        union { u16 h[4]; u64 q8; } pk2;
#pragma unroll
        for (int i = 0; i < 4; ++i) pk2.h[i] = f2bf(src[i]);
        ast64(&p.XD0[(size_t)pn * SXD0 + (size_t)b * KD0 + 1056 + f4], pk2.q8);
    }
}

// out = a @ W2^T: 4 blocks per bq (htile<4); WH2 row-major (unchanged).
__device__ __forceinline__ void dec_D_body(const KParams& p, int t, int htile, int bq,
                                           float* sred) {
    const int pn = (t & 1) ^ 1;
    const int tid = threadIdx.x, lane = tid & 63, w = tid >> 6;
    const int l15 = lane & 15, kq = lane >> 4;
    const int mt = htile & 1, ntl = htile >> 1;
    const int brow = bq * 32 + ntl * 16;
    if (w < 4) {
        const u16* Wr = p.WH2 + (size_t)(mt * 16 + l15) * KH + kq * 8;
        const u16* Xb = p.Abuf + (size_t)(brow + l15) * KH + kq * 8;
        f32x4 acc = {0.f, 0.f, 0.f, 0.f};
#pragma unroll 8
        for (int kb = w * 8; kb < w * 8 + 8; ++kb) {
            const int o = kb * 32;
            acc = mfma16(*(const bf16x8*)(Wr + o), ldx(Xb + o), acc);
        }
#pragma unroll
        for (int q = 0; q < 4; ++q) sred[(w * 64 + lane) * 4 + q] = acc[q];
    }
    __syncthreads();
    if (w == 0) {
        int b = brow + l15;
        union { u16 h[4]; u64 q8; } pk;
#pragma unroll
        for (int q = 0; q < 4; ++q) {
            float s = sred[(0 * 64 + lane) * 4 + q] + sred[(1 * 64 + lane) * 4 + q] +
                      sred[(2 * 64 + lane) * 4 + q] + sred[(3 * 64 + lane) * 4 + q];
            int feat = mt * 16 + kq * 4 + q;
            p.out[(size_t)b * (TOUT * OUTF) + t * OUTF + feat] = s;
            pk.h[q] = f2bf(s);
        }
        ast64(&p.XD0[(size_t)pn * SXD0 + (size_t)b * KD0 + 1024 + mt * 16 + kq * 4], pk.q8);
    }
}

// ---------------- the persistent kernel (group-pipelined, as R8) ----------
__global__ void __launch_bounds__(512, 1) seq2seq_persist(KParams p) {
    __shared__ float sred[4 * 64 * 17];          // 17.4 KB
    __shared__ u16 xls[32 * 2048];               // 128 KB staged X slab
    unsigned* bar = p.bar;
    const int wg = blockIdx.x;

    // ======== encoder: L0 and L1 pipelines, group-local sync ========
    if (wg < 128) {
        int htile, bq; tile_map32(wg, htile, bq);
        unsigned* arrL0 = grp_arr(bar, bq);
        unsigned* genL0 = grp_gen(bar, bq);
        unsigned* genL1 = grp_gen(bar, 4 + bq);
        for (int r = 0; r < 512; ++r) {
            if (r >= 2) waitgen(genL1, (unsigned)(r - 1));
            enc_L0_round(p, r, htile, bq, sred, xls);
            groupbar<32>(arrL0, genL0, (unsigned)(r + 1));
        }
    } else {
        int htile, bq; tile_map32(wg - 128, htile, bq);
        unsigned* arrL1 = grp_arr(bar, 4 + bq);
        unsigned* genL1 = grp_gen(bar, 4 + bq);
        unsigned* genL0 = grp_gen(bar, bq);
        for (int s = 1; s <= 512; ++s) {
            waitgen(genL0, (unsigned)s);
            enc_L1_step(p, s, htile, bq, sred, xls);
            groupbar<32>(arrL1, genL1, (unsigned)s);
        }
    }

    // ======== transition (global) ========
    gridbar(bar, 1);
    transition_body(p);
    gridbar(bar, 2);

    // ======== decoder: 4 independent bq pipelines ========
    if (wg < 128) {
        int htile, bq; tile_map32(wg, htile, bq);
        unsigned* arrA = grp_arr(bar, 8 + bq);  unsigned* genA = grp_gen(bar, 8 + bq);
        unsigned* arrB = grp_arr(bar, 12 + bq); unsigned* genB = grp_gen(bar, 12 + bq);
        unsigned* arrC = grp_arr(bar, 16 + bq); unsigned* genC = grp_gen(bar, 16 + bq);
        unsigned* arrD = grp_arr(bar, 20 + bq); unsigned* genD = grp_gen(bar, 20 + bq);
        for (int t = 0; t < TOUT; ++t) {
            if (t >= 1) waitgen(genD, (unsigned)t);
            dec_A_body(p, t, htile, bq, sred, xls);
            groupbar<32>(arrA, genA, (unsigned)(t + 1));
            dec_B_body(p, t, htile, bq, sred, xls);
            groupbar<32>(arrB, genB, (unsigned)(t + 1));
            dec_C_body(p, t, htile, bq, sred, xls);
            groupbar<32>(arrC, genC, (unsigned)(t + 1));
            if (htile < 4) {
                dec_D_body(p, t, htile, bq, sred);
                groupbar<4>(arrD, genD, (unsigned)(t + 1));
            }
        }
    }
}

// ---------------- host launch ----------------
extern "C" void kernel_launch(void* const* d_in, const int* in_sizes, int n_in,
                              void* d_out, int out_size, void* d_ws, size_t ws_size,
                              hipStream_t stream) {
    const float* enc_input = (const float*)d_in[0];
    const float* dec_input = (const float*)d_in[1];
    const float* enc_Wih0 = (const float*)d_in[2];
    const float* enc_Whh0 = (const float*)d_in[3];
    const float* enc_bih0 = (const float*)d_in[4];
    const float* enc_bhh0 = (const float*)d_in[5];
    const float* enc_Wih1 = (const float*)d_in[6];
    const float* enc_Whh1 = (const float*)d_in[7];
    const float* enc_bih1 = (const float*)d_in[8];
    const float* enc_bhh1 = (const float*)d_in[9];
    const float* dec_Wih0 = (const float*)d_in[10];
    const float* dec_Whh0 = (const float*)d_in[11];
    const float* dec_bih0 = (const float*)d_in[12];
    const float* dec_bhh0 = (const float*)d_in[13];
    const float* dec_Wih1 = (const float*)d_in[14];
    const float* dec_Whh1 = (const float*)d_in[15];
    const float* dec_bih1 = (const float*)d_in[16];
    const float* dec_bhh1 = (const float*)d_in[17];
    const float* out1_W = (const float*)d_in[18];
    const float* out1_b = (const float*)d_in[19];
    const float* out2_W = (const float*)d_in[20];

    char* ws = (char*)d_ws;
    size_t off = 0;
    auto alloc = [&](size_t bytes) { size_t o = off; off = (off + bytes + 255) & ~(size_t)255; return o; };

    u16* W0 = (u16*)(ws + alloc((size_t)H3 * K0 * 2));
    u16* W1 = (u16*)(ws + alloc((size_t)H3 * K1 * 2));
    u16* WD0 = (u16*)(ws + alloc((size_t)H3 * KD0 * 2));
    u16* WD1 = (u16*)(ws + alloc((size_t)H3 * KD1 * 2));
    u16* WH1 = (u16*)(ws + alloc((size_t)Hdim * KH * 2));
    u16* WH2 = (u16*)(ws + alloc((size_t)OUTF * KH * 2));
    float* B0 = (float*)(ws + alloc(4096 * 4));
    float* B1 = (float*)(ws + alloc(4096 * 4));
    float* BD0 = (float*)(ws + alloc(4096 * 4));
    float* BD1 = (float*)(ws + alloc(4096 * 4));
    float* HB = (float*)(ws + alloc(1024 * 4));
    u16* X0 = (u16*)(ws + alloc((size_t)2 * Bsz * K0 * 2));
    u16* X1 = (u16*)(ws + alloc((size_t)2 * Bsz * K1 * 2));
    u16* XD0 = (u16*)(ws + alloc((size_t)2 * Bsz * KD0 * 2));
    u16* XD1 = (u16*)(ws + alloc((size_t)2 * Bsz * KD1 * 2));
    float* H0f = (float*)(ws + alloc((size_t)2 * Bsz * Hdim * 4));
    float* H1f = (float*)(ws + alloc((size_t)2 * Bsz * Hdim * 4));
    u16* Hhead = (u16*)(ws + alloc((size_t)Bsz * KH * 2));
    u16* Abuf = (u16*)(ws + alloc((size_t)Bsz * KH * 2));
    unsigned* bar = (unsigned*)(ws + alloc(BAR_WORDS * 4));

    // --- prologue: fragment-major weight retile + bias/state init ---
    auto nblk = [](long total) { return (unsigned)((total + 255) / 256); };
    pack_tiled<<<nblk((long)32 * 34 * 2 * 3 * 512), 256, 0, stream>>>(enc_Whh0, 1024, enc_Wih0, 64, W0, 34, 3);
    pack_tiled<<<nblk((long)32 * 64 * 2 * 3 * 512), 256, 0, stream>>>(enc_Whh1, 1024, enc_Whh1 ? enc_Wih1 : nullptr, 1024, W1, 64, 3);
    pack_tiled<<<nblk((long)32 * 35 * 2 * 3 * 512), 256, 0, stream>>>(dec_Whh0, 1024, dec_Wih0, 96, WD0, 35, 3);
    pack_tiled<<<nblk((long)32 * 64 * 2 * 3 * 512), 256, 0, stream>>>(dec_Whh1, 1024, dec_Wih1, 1024, WD1, 64, 3);
    pack_tiled<<<nblk((long)32 * 32 * 2 * 1 * 512), 256, 0, stream>>>(out1_W, 1024, nullptr, 0, WH1, 32, 1);
    pack2<<<dim3((KH + 255) / 256, OUTF), 256, 0, stream>>>(out2_W, 1024, nullptr, 0, WH2);
    pack_bias<<<4, 256, 0, stream>>>(enc_bih0, enc_bhh0, enc_bih1, enc_bhh1,
                                     dec_bih0, dec_bhh0, dec_bih1, dec_bhh1,
                                     out1_b, B0, B1, BD0, BD1, HB);
    init_state<<<256, 256, 0, stream>>>(enc_input, X0, X1, H0f, H1f, bar);

    KParams kp;
    kp.enc_input = enc_input; kp.dec_input = dec_input;
    kp.W0 = W0; kp.W1 = W1; kp.WD0 = WD0; kp.WD1 = WD1; kp.WH1 = WH1; kp.WH2 = WH2;
    kp.B0 = B0; kp.B1 = B1; kp.BD0 = BD0; kp.BD1 = BD1; kp.HB = HB;
    kp.X0 = X0; kp.X1 = X1; kp.XD0 = XD0; kp.XD1 = XD1; kp.Hhead = Hhead; kp.Abuf = Abuf;
    kp.H0f = H0f; kp.H1f = H1f;
    kp.out = (float*)d_out;
    kp.bar = bar;

    seq2seq_persist<<<256, 512, 0, stream>>>(kp);
}